// Round 14
// baseline (357.828 us; speedup 1.0000x reference)
//
#include <hip/hip_runtime.h>
#include <math.h>

#define NPT 32768
#define NH 8
#define HD 24
#define EDIM 28
#define NHASH 3
#define NSEG 48
#define NRH 24   // N_HASHES * NUM_HEADS = 24 alpha rows

typedef unsigned long long u64;
typedef unsigned short ushort;
typedef __attribute__((__vector_size__(8 * sizeof(short)))) short bf16x8;
typedef __attribute__((__vector_size__(4 * sizeof(float)))) float floatx4;

__device__ __forceinline__ ushort f2bf(float f) {
    unsigned u = __float_as_uint(f);
    unsigned r = u + 0x7FFF + ((u >> 16) & 1);
    return (ushort)(r >> 16);
}
__device__ __forceinline__ float us2f(ushort u) {
    return __uint_as_float(((unsigned)u) << 16);
}

// ---------------- K0b: RPE weights + folded score matrices (fp64) ----------------
__global__ __launch_bounds__(256) void k0b(
    const float* __restrict__ wrpe, const float* __restrict__ Wq,
    const float* __restrict__ Wk, const float* __restrict__ alphas,
    double* __restrict__ w64, double* __restrict__ cqp64,
    double* __restrict__ Aq, double* __restrict__ Ak, double* __restrict__ ct) {
    __shared__ double sw[16], sc[16];
    int t = threadIdx.x;
    if (t < 16) {
        int h = t >> 1, c = t & 1;
        double s = 0.0;
        for (int i = 0; i < 24; i++)
            for (int j = 0; j < 8; j++)
                s += (double)wrpe[(h * 24 + i) * 16 + c * 8 + j];
        double m = s / 192.0;
        sw[t] = m * m;
        sc[t] = sqrt(2.0) * fabs(m);
        w64[t] = sw[t];
        cqp64[t] = sc[t];
    }
    __syncthreads();
    const double QSCALE = 1.0 / sqrt(24.0);
    for (int idx = t; idx < 24 * NRH; idx += 256) {
        int i = idx / NRH, rh = idx % NRH;
        int h = rh & 7;
        double aq = 0.0, ak = 0.0;
        for (int e = 0; e < 24; e++) {
            double al = (double)alphas[rh * 28 + e];
            aq += (double)Wq[i * 192 + h * 24 + e] * al;
            ak += (double)Wk[i * 192 + h * 24 + e] * al;
        }
        Aq[idx] = aq * QSCALE;
        Ak[idx] = ak;
    }
    if (t < NRH) {
        int h = t & 7;
        ct[t * 4 + 0] = (double)alphas[t * 28 + 24] * sc[h * 2 + 0];
        ct[t * 4 + 1] = (double)alphas[t * 28 + 25] * sc[h * 2 + 1];
        ct[t * 4 + 2] = (double)alphas[t * 28 + 26];
        ct[t * 4 + 3] = (double)alphas[t * 28 + 27];
    }
}

// ---------------- K1b: fp32 LN -> xnf (value path only; 2 points per wave) ----------------
__global__ __launch_bounds__(256) void k1b(
    const float* __restrict__ x, const float* __restrict__ g,
    const float* __restrict__ b, float* __restrict__ xnf) {
    __shared__ float sGB[48];
    int t = threadIdx.x;
    if (t < 24) { sGB[t] = g[t]; sGB[24 + t] = b[t]; }
    __syncthreads();
    int wv = t >> 6, l = t & 63;
    int half = l >> 5, e = l & 31;
    for (int it = 0; it < 8; it++) {
        int n = blockIdx.x * 64 + it * 8 + wv * 2 + half;
        float xv = (e < 24) ? x[(u64)n * 24 + e] : 0.f;
        float s = xv;
        s += __shfl_xor(s, 1); s += __shfl_xor(s, 2); s += __shfl_xor(s, 4);
        s += __shfl_xor(s, 8); s += __shfl_xor(s, 16);
        float mu = s * (1.0f / 24.0f);
        float d = (e < 24) ? (xv - mu) : 0.f;
        float v = d * d;
        v += __shfl_xor(v, 1); v += __shfl_xor(v, 2); v += __shfl_xor(v, 4);
        v += __shfl_xor(v, 8); v += __shfl_xor(v, 16);
        float rstd = 1.0f / sqrtf(v * (1.0f / 24.0f) + 1e-5f);
        if (e < 24) xnf[(u64)n * 24 + e] = d * rstd * sGB[e] + sGB[24 + e];
    }
}

// ---------------- K2s: fused fp64 LN (wave-local butterfly) + hash scores ----------------
__global__ __launch_bounds__(512) void k2s(
    const float* __restrict__ x, const float* __restrict__ n1g,
    const float* __restrict__ n1b, const float* __restrict__ coords,
    const double* __restrict__ Aq, const double* __restrict__ Ak,
    const double* __restrict__ ct, const double* __restrict__ w64,
    u64* __restrict__ keys) {
    __shared__ double sA[2][24][NRH];
    __shared__ double sCt[NRH][4];
    __shared__ double sW64[16];
    __shared__ double sGB[48];
    __shared__ double sXn[8][24];
    int t = threadIdx.x;
    for (int i = t; i < 24 * NRH; i += 512) sA[0][i / NRH][i % NRH] = Aq[i];
    for (int i = t; i < 24 * NRH; i += 512) sA[1][i / NRH][i % NRH] = Ak[i];
    for (int i = t; i < NRH * 4; i += 512) sCt[i / 4][i % 4] = ct[i];
    if (t < 16) sW64[t] = w64[t];
    if (t < 24) { sGB[t] = (double)n1g[t]; sGB[24 + t] = (double)n1b[t]; }
    __syncthreads();
    int wv = t >> 6, l = t & 63;
    for (int g = 0; g < 8; g++) {
        int n = blockIdx.x * 64 + g * 8 + wv;
        double xv = (l < 24) ? (double)x[(u64)n * 24 + l] : 0.0;
        double s = xv;
        s += __shfl_xor(s, 1); s += __shfl_xor(s, 2); s += __shfl_xor(s, 4);
        s += __shfl_xor(s, 8); s += __shfl_xor(s, 16);
        double mu = s / 24.0;
        double d = (l < 24) ? (xv - mu) : 0.0;
        double v2 = d * d;
        v2 += __shfl_xor(v2, 1); v2 += __shfl_xor(v2, 2); v2 += __shfl_xor(v2, 4);
        v2 += __shfl_xor(v2, 8); v2 += __shfl_xor(v2, 16);
        double rstd = 1.0 / sqrt(v2 / 24.0 + 1e-5);
        if (l < 24) sXn[wv][l] = d * rstd * sGB[l] + sGB[24 + l];
        // no barrier: sXn[wv] written and read by the same wave only
        double p0 = (double)coords[(u64)n * 3 + 1];
        double p1 = (double)coords[(u64)n * 3 + 2];
        if (l < 2 * NRH) {
            int qk = l / NRH, rh = l % NRH;
            int h = rh & 7;
            double sqn = sW64[2 * h] * p0 * p0 + sW64[2 * h + 1] * p1 * p1;
            double acc = sCt[rh][0] * p0 + sCt[rh][1] * p1;
            acc += qk ? (sCt[rh][2] - sqn * sCt[rh][3]) : (sCt[rh][3] - sqn * sCt[rh][2]);
            for (int i = 0; i < 24; i++) acc += sXn[wv][i] * sA[qk][i][rh];
            u64 u = (u64)__double_as_longlong(acc);
            if (u >> 63) u = ~u; else u |= 0x8000000000000000ULL;
            u64 key = (u & ~(u64)32767) | (u64)n;
            keys[(u64)l * NPT + n] = key;  // segment = qk*24 + rh = l
        }
    }
}

// ---------------- K2p: column-in-VGPR projections, zero LDS ----------------
// 640 threads: t<576 own one output column (m=t/192, j=t%192), W column in 24 VGPRs,
// x row read via wave-uniform (scalar) loads. Wave 9 writes coords-derived pads.
// varrB padded to stride 32 (64 B-aligned rows).
#define K2P_PTS 64
__global__ __launch_bounds__(640) void k2p(
    const float* __restrict__ xnf,
    const float* __restrict__ Wq, const float* __restrict__ Wk,
    const float* __restrict__ Wv, const float* __restrict__ coords,
    const double* __restrict__ w64, const double* __restrict__ cqp64,
    ushort* __restrict__ qhatB, ushort* __restrict__ khatB, ushort* __restrict__ varrB) {
    int t = threadIdx.x;
    int n0 = blockIdx.x * K2P_PTS;
    if (t < 576) {
        int m = t / 192, jj = t % 192;
        const float* W = (m == 0) ? Wq : ((m == 1) ? Wk : Wv);
        float wc[24];
#pragma unroll
        for (int i = 0; i < 24; i++) wc[i] = W[i * 192 + jj];
        const float scale = (m == 0) ? (float)(1.0 / sqrt(24.0)) : 1.0f;
        int h = jj / 24, e = jj % 24;
        ushort* outp = (m == 0) ? qhatB : ((m == 1) ? khatB : varrB);
        ushort* obase = outp + (u64)h * NPT * 32 + e;
        for (int p = 0; p < K2P_PTS; p++) {
            int n = n0 + p;
            const float* xr = xnf + (u64)n * 24;   // wave-uniform -> s_load
            float acc = 0.f;
#pragma unroll
            for (int i = 0; i < 24; i++) acc += xr[i] * wc[i];
            obase[(u64)n * 32] = f2bf(acc * scale);
        }
    } else {
        int l = t - 576;
        int h2 = l >> 3, e2 = 24 + (l & 7);
        double c0 = cqp64[h2 * 2], c1 = cqp64[h2 * 2 + 1];
        double wa = w64[h2 * 2], wb = w64[h2 * 2 + 1];
        ushort* qb = qhatB + (u64)h2 * NPT * 32 + e2;
        ushort* kb = khatB + (u64)h2 * NPT * 32 + e2;
        for (int p = 0; p < K2P_PTS; p++) {
            int n = n0 + p;
            double p0 = (double)coords[(u64)n * 3 + 1];
            double p1 = (double)coords[(u64)n * 3 + 2];
            float qv, kv;
            if (e2 < 26) {
                int c = e2 - 24;
                float qp = (float)((c ? c1 : c0) * (c ? p1 : p0));
                qv = qp; kv = qp;
            } else if (e2 < 28) {
                double sqn = wa * p0 * p0 + wb * p1 * p1;
                if (e2 == 26) { qv = (float)(-sqn); kv = 1.0f; }
                else          { qv = 1.0f; kv = (float)(-sqn); }
            } else {
                qv = 0.0f; kv = 0.0f;
            }
            qb[(u64)n * 32] = f2bf(qv);
            kb[(u64)n * 32] = f2bf(kv);
        }
    }
}

// ---------------- Bitonic sort v2: register/shfl network, LDS only for j>=512 ----------------
__device__ __forceinline__ u64 shflx64(u64 v, int d) {
    int lo = __shfl_xor((int)(unsigned)v, d);
    int hi = __shfl_xor((int)(unsigned)(v >> 32), d);
    return ((u64)(unsigned)hi << 32) | (unsigned)lo;
}
__device__ __forceinline__ void cswap(u64& a, u64& b, bool up) {
    if ((a > b) == up) { u64 tmp = a; a = b; b = tmp; }
}
__device__ __forceinline__ u64* sslot(u64* s, int i) {
    int a = i << 3;
    a ^= ((a >> 9) & 7) << 4;
    return (u64*)((char*)s + a);
}
__device__ __forceinline__ void reg_passes(u64 e[8], int ib, int K, int jmax) {
    for (int j = jmax; j >= 1; j >>= 1) {
#pragma unroll
        for (int k = 0; k < 8; k++)
            if ((k & j) == 0) cswap(e[k], e[k | j], ((ib + k) & K) == 0);
    }
}
__device__ __forceinline__ void shfl_passes(u64 e[8], int t, int segoff, int K, int jhi, int jlo) {
    for (int j = jhi; j >= jlo; j >>= 1) {
        int d = j >> 3;
        bool lower = (t & d) == 0;
        bool up = ((segoff + ((t & ~d) << 3)) & K) == 0;
        bool keepmin = (lower == up);
#pragma unroll
        for (int k = 0; k < 8; k++) {
            u64 o = shflx64(e[k], d);
            bool ownsm = e[k] < o;
            e[k] = (ownsm == keepmin) ? e[k] : o;
        }
    }
}

__global__ __launch_bounds__(1024) void sort_local_full(u64* keys) {
    __shared__ u64 s[8192];
    int t = threadIdx.x;
    u64 gbase = (u64)blockIdx.x * 8192;
    int segoff = (int)(gbase & 32767);
    int ib = segoff + t * 8;
    u64 e[8];
#pragma unroll
    for (int k = 0; k < 8; k++) e[k] = keys[gbase + t * 8 + k];
    reg_passes(e, ib, 2, 1);
    reg_passes(e, ib, 4, 2);
    reg_passes(e, ib, 8, 4);
    for (int K = 16; K <= 512; K <<= 1) {
        shfl_passes(e, t, segoff, K, K >> 1, 8);
        reg_passes(e, ib, K, 4);
    }
#pragma unroll
    for (int k = 0; k < 8; k++) *sslot(s, t * 8 + k) = e[k];
    __syncthreads();
    for (int K = 1024; K <= 8192; K <<= 1) {
        for (int j = K >> 1; j >= 512; j >>= 1) {
            for (int p = t; p < 4096; p += 1024) {
                int i = ((p & ~(j - 1)) << 1) | (p & (j - 1));
                int i2 = i | j;
                bool up = (((segoff + i) & K) == 0);
                u64 a = *sslot(s, i), b = *sslot(s, i2);
                if ((a > b) == up) { *sslot(s, i) = b; *sslot(s, i2) = a; }
            }
            __syncthreads();
        }
#pragma unroll
        for (int k = 0; k < 8; k++) e[k] = *sslot(s, t * 8 + k);
        shfl_passes(e, t, segoff, K, 256, 8);
        reg_passes(e, ib, K, 4);
        if (K < 8192) {
#pragma unroll
            for (int k = 0; k < 8; k++) *sslot(s, t * 8 + k) = e[k];
            __syncthreads();
        } else {
#pragma unroll
            for (int k = 0; k < 8; k++) keys[gbase + t * 8 + k] = e[k];
        }
    }
}

// minj: stop once minj-blocks are rank-correct sets (bitonic-merge property)
__global__ __launch_bounds__(1024) void sort_local_tail(u64* keys, int K, int minj) {
    __shared__ u64 s[8192];
    int t = threadIdx.x;
    u64 gbase = (u64)blockIdx.x * 8192;
    int segoff = (int)(gbase & 32767);
    int ib = segoff + t * 8;
    for (int i = t; i < 8192; i += 1024) *sslot(s, i) = keys[gbase + i];
    __syncthreads();
    for (int j = 4096; j >= 512; j >>= 1) {
        for (int p = t; p < 4096; p += 1024) {
            int i = ((p & ~(j - 1)) << 1) | (p & (j - 1));
            int i2 = i | j;
            bool up = (((segoff + i) & K) == 0);
            u64 a = *sslot(s, i), b = *sslot(s, i2);
            if ((a > b) == up) { *sslot(s, i) = b; *sslot(s, i2) = a; }
        }
        __syncthreads();
    }
    u64 e[8];
#pragma unroll
    for (int k = 0; k < 8; k++) e[k] = *sslot(s, t * 8 + k);
    shfl_passes(e, t, segoff, K, 256, minj >= 8 ? minj : 8);
    if (minj < 8) reg_passes(e, ib, K, 4);
#pragma unroll
    for (int k = 0; k < 8; k++) keys[gbase + t * 8 + k] = e[k];
}

__global__ void sort_global_pass(u64* keys, int k, int j) {
    int p = blockIdx.x * blockDim.x + threadIdx.x;
    if (p >= NSEG * NPT / 2) return;
    int i = ((p & ~(j - 1)) << 1) | (p & (j - 1));
    int l2 = i | j;
    bool up = (((i & 32767) & k) == 0);
    u64 a = keys[i], b = keys[l2];
    if ((a > b) == up) { keys[i] = b; keys[l2] = a; }
}

// fused K=32768 passes j=16384 + j=8192
__global__ void sort_global2(u64* keys) {
    int p = blockIdx.x * blockDim.x + threadIdx.x;
    if (p >= NSEG * 8192) return;
    int seg = p >> 13, c = p & 8191;
    u64 base = (u64)seg * 32768 + c;
    u64 e0 = keys[base];
    u64 e1 = keys[base + 8192];
    u64 e2 = keys[base + 16384];
    u64 e3 = keys[base + 24576];
    u64 tmp;
    if (e0 > e2) { tmp = e0; e0 = e2; e2 = tmp; }
    if (e1 > e3) { tmp = e1; e1 = e3; e3 = tmp; }
    if (e0 > e1) { tmp = e0; e0 = e1; e1 = tmp; }
    if (e2 > e3) { tmp = e2; e2 = e3; e3 = tmp; }
    keys[base] = e0;
    keys[base + 8192] = e1;
    keys[base + 16384] = e2;
    keys[base + 24576] = e3;
}

// ---------------- K3: block attention via bf16 MFMA ----------------
// launch_bounds(256,6): 6 blocks/CU (LDS 6x26.1KB=157<=160; VGPR cap 85 >= 64 used)
#define VT_STRIDE 136
#define P_STRIDE 72
__global__ __launch_bounds__(256, 6) void k3_attn(
    const u64* __restrict__ keys, const ushort* __restrict__ qhatB,
    const ushort* __restrict__ khatB, const ushort* __restrict__ varrB,
    ushort* __restrict__ ozB) {
    int rh3 = blockIdx.x % 24;
    int b = blockIdx.x / 24;
    int h = rh3 & 7, r = rh3 >> 3;
    __shared__ __align__(16) char smem[6528 + 18432 + 1024];
    short* sVt = (short*)smem;
    short* sP  = (short*)(smem + 6528);
    int* qidx  = (int*)(smem + 6528 + 18432);
    int* kidx  = qidx + 128;
    int t = threadIdx.x;
    int segQ = r * 8 + h, segK = 24 + r * 8 + h;
    if (t < 128) {
        qidx[t] = (int)(keys[(u64)segQ * NPT + b * 128 + t] & 32767ULL);
    } else {
        int i = t - 128;
        kidx[i] = (int)(keys[(u64)segK * NPT + b * 128 + i] & 32767ULL);
    }
    __syncthreads();

    int wave = t >> 6, L = t & 63;
    int quad = L >> 4, n16 = L & 15;

    const bf16x8* Qg = (const bf16x8*)(qhatB + (u64)h * NPT * 32);
    const bf16x8* Kg = (const bf16x8*)(khatB + (u64)h * NPT * 32);
    bf16x8 afr[2];
#pragma unroll
    for (int rtg = 0; rtg < 2; rtg++) {
        int qi = qidx[wave * 32 + rtg * 16 + n16];
        afr[rtg] = Qg[(u64)qi * 4 + quad];
    }
    bf16x8 bfr[8];
#pragma unroll
    for (int ct = 0; ct < 8; ct++) {
        int ki = kidx[ct * 16 + n16];
        bfr[ct] = Kg[(u64)ki * 4 + quad];
    }
    // stage V transposed: one thread per row, 3 vector loads (64 B-aligned rows)
    if (t < 128) {
        int ki = kidx[t];
        const bf16x8* vr = (const bf16x8*)(varrB + ((u64)h * NPT + ki) * 32);
        bf16x8 v0 = vr[0], v1 = vr[1], v2 = vr[2];
#pragma unroll
        for (int e = 0; e < 8; e++) {
            sVt[e * VT_STRIDE + t]        = v0[e];
            sVt[(8 + e) * VT_STRIDE + t]  = v1[e];
            sVt[(16 + e) * VT_STRIDE + t] = v2[e];
        }
    }
    __syncthreads();

    floatx4 acc[2][8];
#pragma unroll
    for (int rtg = 0; rtg < 2; rtg++)
#pragma unroll
        for (int ct = 0; ct < 8; ct++)
            acc[rtg][ct] = (floatx4){0.f, 0.f, 0.f, 0.f};
#pragma unroll
    for (int ct = 0; ct < 8; ct++) {
#pragma unroll
        for (int rtg = 0; rtg < 2; rtg++)
            acc[rtg][ct] = __builtin_amdgcn_mfma_f32_16x16x32_bf16(afr[rtg], bfr[ct], acc[rtg][ct], 0, 0, 0);
    }

    float mrow[2][4], srow[2][4];
#pragma unroll
    for (int rtg = 0; rtg < 2; rtg++) {
#pragma unroll
        for (int rg = 0; rg < 4; rg++) {
            float m = -1e30f;
#pragma unroll
            for (int ct = 0; ct < 8; ct++) m = fmaxf(m, acc[rtg][ct][rg]);
            m = fmaxf(m, __shfl_xor(m, 1));
            m = fmaxf(m, __shfl_xor(m, 2));
            m = fmaxf(m, __shfl_xor(m, 4));
            m = fmaxf(m, __shfl_xor(m, 8));
            mrow[rtg][rg] = m;
            float s = 0.0f;
            int row = wave * 32 + rtg * 16 + quad * 4 + rg;
#pragma unroll
            for (int ct = 0; ct < 8; ct++) {
                float p = __expf(acc[rtg][ct][rg] - m);
                s += p;
                if (ct < 4) sP[row * P_STRIDE + ct * 16 + n16] = (short)f2bf(p);
            }
            s += __shfl_xor(s, 1);
            s += __shfl_xor(s, 2);
            s += __shfl_xor(s, 4);
            s += __shfl_xor(s, 8);
            srow[rtg][rg] = s;
        }
    }

    floatx4 occ[2][2];
#pragma unroll
    for (int rtg = 0; rtg < 2; rtg++)
#pragma unroll
        for (int ct2 = 0; ct2 < 2; ct2++)
            occ[rtg][ct2] = (floatx4){0.f, 0.f, 0.f, 0.f};
#pragma unroll
    for (int ks = 0; ks < 2; ks++) {
        bf16x8 bv[2], av[2];
#pragma unroll
        for (int ct2 = 0; ct2 < 2; ct2++)
            bv[ct2] = *(const bf16x8*)(sVt + (ct2 * 16 + n16) * VT_STRIDE + ks * 32 + quad * 8);
#pragma unroll
        for (int rtg = 0; rtg < 2; rtg++)
            av[rtg] = *(const bf16x8*)(sP + (wave * 32 + rtg * 16 + n16) * P_STRIDE + ks * 32 + quad * 8);
#pragma unroll
        for (int rtg = 0; rtg < 2; rtg++)
#pragma unroll
            for (int ct2 = 0; ct2 < 2; ct2++)
                occ[rtg][ct2] = __builtin_amdgcn_mfma_f32_16x16x32_bf16(av[rtg], bv[ct2], occ[rtg][ct2], 0, 0, 0);
    }
#pragma unroll
    for (int rtg = 0; rtg < 2; rtg++) {
#pragma unroll
        for (int rg = 0; rg < 4; rg++) {
            int row = wave * 32 + rtg * 16 + quad * 4 + rg;
#pragma unroll
            for (int ct = 4; ct < 8; ct++) {
                float p = __expf(acc[rtg][ct][rg] - mrow[rtg][rg]);
                sP[row * P_STRIDE + (ct - 4) * 16 + n16] = (short)f2bf(p);
            }
        }
    }
#pragma unroll
    for (int ks = 2; ks < 4; ks++) {
        bf16x8 bv[2], av[2];
#pragma unroll
        for (int ct2 = 0; ct2 < 2; ct2++)
            bv[ct2] = *(const bf16x8*)(sVt + (ct2 * 16 + n16) * VT_STRIDE + ks * 32 + quad * 8);
#pragma unroll
        for (int rtg = 0; rtg < 2; rtg++)
            av[rtg] = *(const bf16x8*)(sP + (wave * 32 + rtg * 16 + n16) * P_STRIDE + (ks - 2) * 32 + quad * 8);
#pragma unroll
        for (int rtg = 0; rtg < 2; rtg++)
#pragma unroll
            for (int ct2 = 0; ct2 < 2; ct2++)
                occ[rtg][ct2] = __builtin_amdgcn_mfma_f32_16x16x32_bf16(av[rtg], bv[ct2], occ[rtg][ct2], 0, 0, 0);
    }

#pragma unroll
    for (int rtg = 0; rtg < 2; rtg++) {
#pragma unroll
        for (int rg = 0; rg < 4; rg++) {
            int row = wave * 32 + rtg * 16 + quad * 4 + rg;
            int oi = qidx[row];
            float inv = 1.0f / srow[rtg][rg];
            ushort* orow = ozB + ((u64)segQ * NPT + oi) * 32;
#pragma unroll
            for (int ct2 = 0; ct2 < 2; ct2++) {
                int col = ct2 * 16 + n16;
                if (col < 24) orow[col] = f2bf(occ[rtg][ct2][rg] * inv);
            }
            if (n16 == 0)
                *(float*)(orow + 24) = mrow[rtg][rg] + __logf(srow[rtg][rg]);
        }
    }
}

// ---------------- K4: hash combine + Wo + residual + LN2 + FFN (fp32, 32 pts/block) ----------------
// Wo transposed in LDS; attn/Wo read as float4 (b128) to halve LDS issue count.
#define K4PTS 32
#define AT_STR 196   // floats; 16B-aligned rows, 4-bank row offset
__global__ __launch_bounds__(256) void k4_final(
    const ushort* __restrict__ ozB,
    const float* __restrict__ x,
    const float* __restrict__ Wo, const float* __restrict__ bo,
    const float* __restrict__ g2, const float* __restrict__ b2,
    const float* __restrict__ W1, const float* __restrict__ b1f,
    const float* __restrict__ W2, const float* __restrict__ b2f,
    float* __restrict__ out) {
    __shared__ __align__(16) float sWoT[24][AT_STR];
    __shared__ float sW1[24 * 24], sW2[24 * 24];
    __shared__ float sB[5 * 24];
    __shared__ __align__(16) float attn[K4PTS][AT_STR];
    __shared__ float xrow[K4PTS][25];
    __shared__ float h2row[K4PTS][25];
    __shared__ float ffrow[K4PTS][25];
    int t = threadIdx.x;
    int base = blockIdx.x * K4PTS;
    for (int i = t; i < 4608; i += 256) sWoT[i % 24][i / 24] = Wo[i];
    for (int i = t; i < 576; i += 256) { sW1[i] = W1[i]; sW2[i] = W2[i]; }
    if (t < 24) {
        sB[t] = bo[t]; sB[24 + t] = g2[t]; sB[48 + t] = b2[t];
        sB[72 + t] = b1f[t]; sB[96 + t] = b2f[t];
    }
    {
        int p = t >> 3, h = t & 7;
        int n = base + p;
        const ushort* r0 = ozB + ((u64)(0 * 8 + h) * NPT + n) * 32;
        const ushort* r1 = ozB + ((u64)(1 * 8 + h) * NPT + n) * 32;
        const ushort* r2 = ozB + ((u64)(2 * 8 + h) * NPT + n) * 32;
        float z0 = *(const float*)(r0 + 24);
        float z1 = *(const float*)(r1 + 24);
        float z2 = *(const float*)(r2 + 24);
        float zm = fmaxf(z0, fmaxf(z1, z2));
        float e0 = __expf(z0 - zm), e1 = __expf(z1 - zm), e2 = __expf(z2 - zm);
        float inv = 1.0f / (e0 + e1 + e2);
        float w0 = e0 * inv, w1 = e1 * inv, w2 = e2 * inv;
#pragma unroll
        for (int e = 0; e < 24; e++)
            attn[p][h * 24 + e] = w0 * us2f(r0[e]) + w1 * us2f(r1[e]) + w2 * us2f(r2[e]);
    }
    __syncthreads();
    int p = t >> 3, oe = t & 7;
    int n = base + p;
    {
        const floatx4* ap = (const floatx4*)&attn[p][0];
        const floatx4* w0p = (const floatx4*)&sWoT[oe][0];
        const floatx4* w1p = (const floatx4*)&sWoT[oe + 8][0];
        const floatx4* w2p = (const floatx4*)&sWoT[oe + 16][0];
        floatx4 A0 = {0.f, 0.f, 0.f, 0.f}, A1 = A0, A2 = A0;
        for (int ii = 0; ii < 48; ii++) {
            floatx4 av = ap[ii];
            A0 += av * w0p[ii];
            A1 += av * w1p[ii];
            A2 += av * w2p[ii];
        }
        float a0 = A0[0] + A0[1] + A0[2] + A0[3];
        float a1 = A1[0] + A1[1] + A1[2] + A1[3];
        float a2 = A2[0] + A2[1] + A2[2] + A2[3];
        xrow[p][oe]      = x[n * 24 + oe]      + a0 + sB[oe];
        xrow[p][oe + 8]  = x[n * 24 + oe + 8]  + a1 + sB[oe + 8];
        xrow[p][oe + 16] = x[n * 24 + oe + 16] + a2 + sB[oe + 16];
    }
    float mu, rstd;
    {
        float s = xrow[p][oe] + xrow[p][oe + 8] + xrow[p][oe + 16];
        s += __shfl_xor(s, 1); s += __shfl_xor(s, 2); s += __shfl_xor(s, 4);
        mu = s / 24.0f;
        float v0 = xrow[p][oe] - mu, v1 = xrow[p][oe + 8] - mu, v2 = xrow[p][oe + 16] - mu;
        float v = v0 * v0 + v1 * v1 + v2 * v2;
        v += __shfl_xor(v, 1); v += __shfl_xor(v, 2); v += __shfl_xor(v, 4);
        rstd = 1.0f / sqrtf(v / 24.0f + 1e-5f);
    }
    h2row[p][oe]      = (xrow[p][oe] - mu)      * rstd * sB[24 + oe]      + sB[48 + oe];
    h2row[p][oe + 8]  = (xrow[p][oe + 8] - mu)  * rstd * sB[24 + oe + 8]  + sB[48 + oe + 8];
    h2row[p][oe + 16] = (xrow[p][oe + 16] - mu) * rstd * sB[24 + oe + 16] + sB[48 + oe + 16];
    {
        float a0 = sB[72 + oe], a1 = sB[72 + oe + 8], a2 = sB[72 + oe + 16];
        for (int i = 0; i < 24; i++) {
            float hi = h2row[p][i];
            a0 += hi * sW1[i * 24 + oe];
            a1 += hi * sW1[i * 24 + oe + 8];
            a2 += hi * sW1[i * 24 + oe + 16];
        }
        ffrow[p][oe]      = fmaxf(a0, 0.f);
        ffrow[p][oe + 8]  = fmaxf(a1, 0.f);
        ffrow[p][oe + 16] = fmaxf(a2, 0.f);
    }
    {
        float a0 = sB[96 + oe], a1 = sB[96 + oe + 8], a2 = sB[96 + oe + 16];
        for (int i = 0; i < 24; i++) {
            float fi = ffrow[p][i];
            a0 += fi * sW2[i * 24 + oe];
            a1 += fi * sW2[i * 24 + oe + 8];
            a2 += fi * sW2[i * 24 + oe + 16];
        }
        out[n * 24 + oe]      = xrow[p][oe]      + a0;
        out[n * 24 + oe + 8]  = xrow[p][oe + 8]  + a1;
        out[n * 24 + oe + 16] = xrow[p][oe + 16] + a2;
    }
}

extern "C" void kernel_launch(void* const* d_in, const int* in_sizes, int n_in,
                              void* d_out, int out_size, void* d_ws, size_t ws_size,
                              hipStream_t stream) {
    const float* x      = (const float*)d_in[0];
    const float* coords = (const float*)d_in[1];
    const float* n1g    = (const float*)d_in[2];
    const float* n1b    = (const float*)d_in[3];
    const float* Wq     = (const float*)d_in[4];
    const float* Wk     = (const float*)d_in[5];
    const float* Wv     = (const float*)d_in[6];
    const float* wrpe   = (const float*)d_in[7];
    const float* Wo     = (const float*)d_in[8];
    const float* bo     = (const float*)d_in[9];
    const float* n2g    = (const float*)d_in[10];
    const float* n2b    = (const float*)d_in[11];
    const float* W1     = (const float*)d_in[12];
    const float* b1     = (const float*)d_in[13];
    const float* W2     = (const float*)d_in[14];
    const float* b2     = (const float*)d_in[15];
    const float* alphas = (const float*)d_in[16];

    char* ws = (char*)d_ws;
    size_t off = 0;
    auto alloc = [&](size_t bytes) -> void* {
        void* p = ws + off;
        off = (off + bytes + 255) & ~(size_t)255;
        return p;
    };
    double* w64   = (double*)alloc(256);
    double* cqp   = (double*)alloc(256);
    double* Aq    = (double*)alloc(24 * NRH * 8);
    double* Ak    = (double*)alloc(24 * NRH * 8);
    double* ct    = (double*)alloc(NRH * 4 * 8);
    float*  xnf   = (float*)alloc((size_t)NPT * 24 * 4);
    ushort* qhatB = (ushort*)alloc((size_t)NH * NPT * 32 * 2);
    ushort* khatB = (ushort*)alloc((size_t)NH * NPT * 32 * 2);
    ushort* varrB = (ushort*)alloc((size_t)NH * NPT * 32 * 2);
    u64*    keys  = (u64*)alloc((size_t)NSEG * NPT * 8);
    ushort* ozB   = (ushort*)alloc((size_t)NHASH * NH * NPT * 32 * 2);
    if (off > ws_size) return;

    k0b<<<1, 256, 0, stream>>>(wrpe, Wq, Wk, alphas, w64, cqp, Aq, Ak, ct);
    k1b<<<NPT / 64, 256, 0, stream>>>(x, n1g, n1b, xnf);
    k2s<<<NPT / 64, 512, 0, stream>>>(x, n1g, n1b, coords, Aq, Ak, ct, w64, keys);
    k2p<<<NPT / K2P_PTS, 640, 0, stream>>>(xnf, Wq, Wk, Wv, coords, w64, cqp,
                                           qhatB, khatB, varrB);
    sort_local_full<<<192, 1024, 0, stream>>>(keys);
    sort_global_pass<<<3072, 256, 0, stream>>>(keys, 16384, 8192);
    sort_local_tail<<<192, 1024, 0, stream>>>(keys, 16384, 1);
    sort_global2<<<NSEG * 8192 / 256, 256, 0, stream>>>(keys);
    sort_local_tail<<<192, 1024, 0, stream>>>(keys, 32768, 128);
    k3_attn<<<256 * 8 * 3, 256, 0, stream>>>(keys, qhatB, khatB, varrB, ozB);
    k4_final<<<NPT / K4PTS, 256, 0, stream>>>(ozB, x, Wo, bo, n2g, n2b,
                                              W1, b1, W2, b2, (float*)d_out);
}

// Round 15
// 321.098 us; speedup vs baseline: 1.1144x; 1.1144x over previous
//
#include <hip/hip_runtime.h>
#include <math.h>

#define NPT 32768
#define NH 8
#define HD 24
#define EDIM 28
#define NHASH 3
#define NSEG 48
#define NRH 24   // N_HASHES * NUM_HEADS = 24 alpha rows

typedef unsigned long long u64;
typedef unsigned short ushort;
typedef __attribute__((__vector_size__(8 * sizeof(short)))) short bf16x8;
typedef __attribute__((__vector_size__(4 * sizeof(float)))) float floatx4;

__device__ __forceinline__ ushort f2bf(float f) {
    unsigned u = __float_as_uint(f);
    unsigned r = u + 0x7FFF + ((u >> 16) & 1);
    return (ushort)(r >> 16);
}
__device__ __forceinline__ float us2f(ushort u) {
    return __uint_as_float(((unsigned)u) << 16);
}

// ---------------- K0b: RPE weights + folded score matrices (fp64) ----------------
__global__ __launch_bounds__(256) void k0b(
    const float* __restrict__ wrpe, const float* __restrict__ Wq,
    const float* __restrict__ Wk, const float* __restrict__ alphas,
    double* __restrict__ w64, double* __restrict__ cqp64,
    double* __restrict__ Aq, double* __restrict__ Ak, double* __restrict__ ct) {
    __shared__ double sw[16], sc[16];
    int t = threadIdx.x;
    if (t < 16) {
        int h = t >> 1, c = t & 1;
        double s = 0.0;
        for (int i = 0; i < 24; i++)
            for (int j = 0; j < 8; j++)
                s += (double)wrpe[(h * 24 + i) * 16 + c * 8 + j];
        double m = s / 192.0;
        sw[t] = m * m;
        sc[t] = sqrt(2.0) * fabs(m);
        w64[t] = sw[t];
        cqp64[t] = sc[t];
    }
    __syncthreads();
    const double QSCALE = 1.0 / sqrt(24.0);
    for (int idx = t; idx < 24 * NRH; idx += 256) {
        int i = idx / NRH, rh = idx % NRH;
        int h = rh & 7;
        double aq = 0.0, ak = 0.0;
        for (int e = 0; e < 24; e++) {
            double al = (double)alphas[rh * 28 + e];
            aq += (double)Wq[i * 192 + h * 24 + e] * al;
            ak += (double)Wk[i * 192 + h * 24 + e] * al;
        }
        Aq[idx] = aq * QSCALE;
        Ak[idx] = ak;
    }
    if (t < NRH) {
        int h = t & 7;
        ct[t * 4 + 0] = (double)alphas[t * 28 + 24] * sc[h * 2 + 0];
        ct[t * 4 + 1] = (double)alphas[t * 28 + 25] * sc[h * 2 + 1];
        ct[t * 4 + 2] = (double)alphas[t * 28 + 26];
        ct[t * 4 + 3] = (double)alphas[t * 28 + 27];
    }
}

// ---------------- K1b: fp32 LN -> xnf (value path only; 2 points per wave) ----------------
__global__ __launch_bounds__(256) void k1b(
    const float* __restrict__ x, const float* __restrict__ g,
    const float* __restrict__ b, float* __restrict__ xnf) {
    __shared__ float sGB[48];
    int t = threadIdx.x;
    if (t < 24) { sGB[t] = g[t]; sGB[24 + t] = b[t]; }
    __syncthreads();
    int wv = t >> 6, l = t & 63;
    int half = l >> 5, e = l & 31;
    for (int it = 0; it < 8; it++) {
        int n = blockIdx.x * 64 + it * 8 + wv * 2 + half;
        float xv = (e < 24) ? x[(u64)n * 24 + e] : 0.f;
        float s = xv;
        s += __shfl_xor(s, 1); s += __shfl_xor(s, 2); s += __shfl_xor(s, 4);
        s += __shfl_xor(s, 8); s += __shfl_xor(s, 16);
        float mu = s * (1.0f / 24.0f);
        float d = (e < 24) ? (xv - mu) : 0.f;
        float v = d * d;
        v += __shfl_xor(v, 1); v += __shfl_xor(v, 2); v += __shfl_xor(v, 4);
        v += __shfl_xor(v, 8); v += __shfl_xor(v, 16);
        float rstd = 1.0f / sqrtf(v * (1.0f / 24.0f) + 1e-5f);
        if (e < 24) xnf[(u64)n * 24 + e] = d * rstd * sGB[e] + sGB[24 + e];
    }
}

// ---------------- K2s: fused fp64 LN (wave-local butterfly) + hash scores ----------------
__global__ __launch_bounds__(512) void k2s(
    const float* __restrict__ x, const float* __restrict__ n1g,
    const float* __restrict__ n1b, const float* __restrict__ coords,
    const double* __restrict__ Aq, const double* __restrict__ Ak,
    const double* __restrict__ ct, const double* __restrict__ w64,
    u64* __restrict__ keys) {
    __shared__ double sA[2][24][NRH];
    __shared__ double sCt[NRH][4];
    __shared__ double sW64[16];
    __shared__ double sGB[48];
    __shared__ double sXn[8][24];
    int t = threadIdx.x;
    for (int i = t; i < 24 * NRH; i += 512) sA[0][i / NRH][i % NRH] = Aq[i];
    for (int i = t; i < 24 * NRH; i += 512) sA[1][i / NRH][i % NRH] = Ak[i];
    for (int i = t; i < NRH * 4; i += 512) sCt[i / 4][i % 4] = ct[i];
    if (t < 16) sW64[t] = w64[t];
    if (t < 24) { sGB[t] = (double)n1g[t]; sGB[24 + t] = (double)n1b[t]; }
    __syncthreads();
    int wv = t >> 6, l = t & 63;
    for (int g = 0; g < 8; g++) {
        int n = blockIdx.x * 64 + g * 8 + wv;
        double xv = (l < 24) ? (double)x[(u64)n * 24 + l] : 0.0;
        double s = xv;
        s += __shfl_xor(s, 1); s += __shfl_xor(s, 2); s += __shfl_xor(s, 4);
        s += __shfl_xor(s, 8); s += __shfl_xor(s, 16);
        double mu = s / 24.0;
        double d = (l < 24) ? (xv - mu) : 0.0;
        double v2 = d * d;
        v2 += __shfl_xor(v2, 1); v2 += __shfl_xor(v2, 2); v2 += __shfl_xor(v2, 4);
        v2 += __shfl_xor(v2, 8); v2 += __shfl_xor(v2, 16);
        double rstd = 1.0 / sqrt(v2 / 24.0 + 1e-5);
        if (l < 24) sXn[wv][l] = d * rstd * sGB[l] + sGB[24 + l];
        // no barrier: sXn[wv] written and read by the same wave only
        double p0 = (double)coords[(u64)n * 3 + 1];
        double p1 = (double)coords[(u64)n * 3 + 2];
        if (l < 2 * NRH) {
            int qk = l / NRH, rh = l % NRH;
            int h = rh & 7;
            double sqn = sW64[2 * h] * p0 * p0 + sW64[2 * h + 1] * p1 * p1;
            double acc = sCt[rh][0] * p0 + sCt[rh][1] * p1;
            acc += qk ? (sCt[rh][2] - sqn * sCt[rh][3]) : (sCt[rh][3] - sqn * sCt[rh][2]);
            for (int i = 0; i < 24; i++) acc += sXn[wv][i] * sA[qk][i][rh];
            u64 u = (u64)__double_as_longlong(acc);
            if (u >> 63) u = ~u; else u |= 0x8000000000000000ULL;
            u64 key = (u & ~(u64)32767) | (u64)n;
            keys[(u64)l * NPT + n] = key;  // segment = qk*24 + rh = l
        }
    }
}

// ---------------- K2p: column-in-VGPR projections, zero LDS ----------------
#define K2P_PTS 64
__global__ __launch_bounds__(640) void k2p(
    const float* __restrict__ xnf,
    const float* __restrict__ Wq, const float* __restrict__ Wk,
    const float* __restrict__ Wv, const float* __restrict__ coords,
    const double* __restrict__ w64, const double* __restrict__ cqp64,
    ushort* __restrict__ qhatB, ushort* __restrict__ khatB, ushort* __restrict__ varrB) {
    int t = threadIdx.x;
    int n0 = blockIdx.x * K2P_PTS;
    if (t < 576) {
        int m = t / 192, jj = t % 192;
        const float* W = (m == 0) ? Wq : ((m == 1) ? Wk : Wv);
        float wc[24];
#pragma unroll
        for (int i = 0; i < 24; i++) wc[i] = W[i * 192 + jj];
        const float scale = (m == 0) ? (float)(1.0 / sqrt(24.0)) : 1.0f;
        int h = jj / 24, e = jj % 24;
        ushort* outp = (m == 0) ? qhatB : ((m == 1) ? khatB : varrB);
        ushort* obase = outp + (u64)h * NPT * 32 + e;
        for (int p = 0; p < K2P_PTS; p++) {
            int n = n0 + p;
            const float* xr = xnf + (u64)n * 24;   // wave-uniform -> s_load
            float acc = 0.f;
#pragma unroll
            for (int i = 0; i < 24; i++) acc += xr[i] * wc[i];
            obase[(u64)n * 32] = f2bf(acc * scale);
        }
    } else {
        int l = t - 576;
        int h2 = l >> 3, e2 = 24 + (l & 7);
        double c0 = cqp64[h2 * 2], c1 = cqp64[h2 * 2 + 1];
        double wa = w64[h2 * 2], wb = w64[h2 * 2 + 1];
        ushort* qb = qhatB + (u64)h2 * NPT * 32 + e2;
        ushort* kb = khatB + (u64)h2 * NPT * 32 + e2;
        for (int p = 0; p < K2P_PTS; p++) {
            int n = n0 + p;
            double p0 = (double)coords[(u64)n * 3 + 1];
            double p1 = (double)coords[(u64)n * 3 + 2];
            float qv, kv;
            if (e2 < 26) {
                int c = e2 - 24;
                float qp = (float)((c ? c1 : c0) * (c ? p1 : p0));
                qv = qp; kv = qp;
            } else if (e2 < 28) {
                double sqn = wa * p0 * p0 + wb * p1 * p1;
                if (e2 == 26) { qv = (float)(-sqn); kv = 1.0f; }
                else          { qv = 1.0f; kv = (float)(-sqn); }
            } else {
                qv = 0.0f; kv = 0.0f;
            }
            qb[(u64)n * 32] = f2bf(qv);
            kb[(u64)n * 32] = f2bf(kv);
        }
    }
}

// ---------------- Bitonic sort v2: register/shfl network, LDS only for j>=512 ----------------
__device__ __forceinline__ u64 shflx64(u64 v, int d) {
    int lo = __shfl_xor((int)(unsigned)v, d);
    int hi = __shfl_xor((int)(unsigned)(v >> 32), d);
    return ((u64)(unsigned)hi << 32) | (unsigned)lo;
}
__device__ __forceinline__ void cswap(u64& a, u64& b, bool up) {
    if ((a > b) == up) { u64 tmp = a; a = b; b = tmp; }
}
__device__ __forceinline__ u64* sslot(u64* s, int i) {
    int a = i << 3;
    a ^= ((a >> 9) & 7) << 4;
    return (u64*)((char*)s + a);
}
__device__ __forceinline__ void reg_passes(u64 e[8], int ib, int K, int jmax) {
    for (int j = jmax; j >= 1; j >>= 1) {
#pragma unroll
        for (int k = 0; k < 8; k++)
            if ((k & j) == 0) cswap(e[k], e[k | j], ((ib + k) & K) == 0);
    }
}
__device__ __forceinline__ void shfl_passes(u64 e[8], int t, int segoff, int K, int jhi, int jlo) {
    for (int j = jhi; j >= jlo; j >>= 1) {
        int d = j >> 3;
        bool lower = (t & d) == 0;
        bool up = ((segoff + ((t & ~d) << 3)) & K) == 0;
        bool keepmin = (lower == up);
#pragma unroll
        for (int k = 0; k < 8; k++) {
            u64 o = shflx64(e[k], d);
            bool ownsm = e[k] < o;
            e[k] = (ownsm == keepmin) ? e[k] : o;
        }
    }
}

__global__ __launch_bounds__(1024) void sort_local_full(u64* keys) {
    __shared__ u64 s[8192];
    int t = threadIdx.x;
    u64 gbase = (u64)blockIdx.x * 8192;
    int segoff = (int)(gbase & 32767);
    int ib = segoff + t * 8;
    u64 e[8];
#pragma unroll
    for (int k = 0; k < 8; k++) e[k] = keys[gbase + t * 8 + k];
    reg_passes(e, ib, 2, 1);
    reg_passes(e, ib, 4, 2);
    reg_passes(e, ib, 8, 4);
    for (int K = 16; K <= 512; K <<= 1) {
        shfl_passes(e, t, segoff, K, K >> 1, 8);
        reg_passes(e, ib, K, 4);
    }
#pragma unroll
    for (int k = 0; k < 8; k++) *sslot(s, t * 8 + k) = e[k];
    __syncthreads();
    for (int K = 1024; K <= 8192; K <<= 1) {
        for (int j = K >> 1; j >= 512; j >>= 1) {
            for (int p = t; p < 4096; p += 1024) {
                int i = ((p & ~(j - 1)) << 1) | (p & (j - 1));
                int i2 = i | j;
                bool up = (((segoff + i) & K) == 0);
                u64 a = *sslot(s, i), b = *sslot(s, i2);
                if ((a > b) == up) { *sslot(s, i) = b; *sslot(s, i2) = a; }
            }
            __syncthreads();
        }
#pragma unroll
        for (int k = 0; k < 8; k++) e[k] = *sslot(s, t * 8 + k);
        shfl_passes(e, t, segoff, K, 256, 8);
        reg_passes(e, ib, K, 4);
        if (K < 8192) {
#pragma unroll
            for (int k = 0; k < 8; k++) *sslot(s, t * 8 + k) = e[k];
            __syncthreads();
        } else {
#pragma unroll
            for (int k = 0; k < 8; k++) keys[gbase + t * 8 + k] = e[k];
        }
    }
}

// minj: stop once minj-blocks are rank-correct sets (bitonic-merge property)
__global__ __launch_bounds__(1024) void sort_local_tail(u64* keys, int K, int minj) {
    __shared__ u64 s[8192];
    int t = threadIdx.x;
    u64 gbase = (u64)blockIdx.x * 8192;
    int segoff = (int)(gbase & 32767);
    int ib = segoff + t * 8;
    for (int i = t; i < 8192; i += 1024) *sslot(s, i) = keys[gbase + i];
    __syncthreads();
    for (int j = 4096; j >= 512; j >>= 1) {
        for (int p = t; p < 4096; p += 1024) {
            int i = ((p & ~(j - 1)) << 1) | (p & (j - 1));
            int i2 = i | j;
            bool up = (((segoff + i) & K) == 0);
            u64 a = *sslot(s, i), b = *sslot(s, i2);
            if ((a > b) == up) { *sslot(s, i) = b; *sslot(s, i2) = a; }
        }
        __syncthreads();
    }
    u64 e[8];
#pragma unroll
    for (int k = 0; k < 8; k++) e[k] = *sslot(s, t * 8 + k);
    shfl_passes(e, t, segoff, K, 256, minj >= 8 ? minj : 8);
    if (minj < 8) reg_passes(e, ib, K, 4);
#pragma unroll
    for (int k = 0; k < 8; k++) keys[gbase + t * 8 + k] = e[k];
}

__global__ void sort_global_pass(u64* keys, int k, int j) {
    int p = blockIdx.x * blockDim.x + threadIdx.x;
    if (p >= NSEG * NPT / 2) return;
    int i = ((p & ~(j - 1)) << 1) | (p & (j - 1));
    int l2 = i | j;
    bool up = (((i & 32767) & k) == 0);
    u64 a = keys[i], b = keys[l2];
    if ((a > b) == up) { keys[i] = b; keys[l2] = a; }
}

// fused K=32768 passes j=16384 + j=8192
__global__ void sort_global2(u64* keys) {
    int p = blockIdx.x * blockDim.x + threadIdx.x;
    if (p >= NSEG * 8192) return;
    int seg = p >> 13, c = p & 8191;
    u64 base = (u64)seg * 32768 + c;
    u64 e0 = keys[base];
    u64 e1 = keys[base + 8192];
    u64 e2 = keys[base + 16384];
    u64 e3 = keys[base + 24576];
    u64 tmp;
    if (e0 > e2) { tmp = e0; e0 = e2; e2 = tmp; }
    if (e1 > e3) { tmp = e1; e1 = e3; e3 = tmp; }
    if (e0 > e1) { tmp = e0; e0 = e1; e1 = tmp; }
    if (e2 > e3) { tmp = e2; e2 = e3; e3 = tmp; }
    keys[base] = e0;
    keys[base + 8192] = e1;
    keys[base + 16384] = e2;
    keys[base + 24576] = e3;
}

// ---------------- K3: block attention via bf16 MFMA ----------------
// launch_bounds(256,4): 4 blocks/CU, VGPR cap 128 (no spills; r14's bound=6 spilled)
#define VT_STRIDE 136
#define P_STRIDE 72
__global__ __launch_bounds__(256, 4) void k3_attn(
    const u64* __restrict__ keys, const ushort* __restrict__ qhatB,
    const ushort* __restrict__ khatB, const ushort* __restrict__ varrB,
    ushort* __restrict__ ozB) {
    int rh3 = blockIdx.x % 24;
    int b = blockIdx.x / 24;
    int h = rh3 & 7, r = rh3 >> 3;
    __shared__ __align__(16) char smem[6528 + 18432 + 1024];
    short* sVt = (short*)smem;
    short* sP  = (short*)(smem + 6528);
    int* qidx  = (int*)(smem + 6528 + 18432);
    int* kidx  = qidx + 128;
    int t = threadIdx.x;
    int segQ = r * 8 + h, segK = 24 + r * 8 + h;
    if (t < 128) {
        qidx[t] = (int)(keys[(u64)segQ * NPT + b * 128 + t] & 32767ULL);
    } else {
        int i = t - 128;
        kidx[i] = (int)(keys[(u64)segK * NPT + b * 128 + i] & 32767ULL);
    }
    __syncthreads();

    int wave = t >> 6, L = t & 63;
    int quad = L >> 4, n16 = L & 15;

    const bf16x8* Qg = (const bf16x8*)(qhatB + (u64)h * NPT * 32);
    const bf16x8* Kg = (const bf16x8*)(khatB + (u64)h * NPT * 32);
    bf16x8 afr[2];
#pragma unroll
    for (int rtg = 0; rtg < 2; rtg++) {
        int qi = qidx[wave * 32 + rtg * 16 + n16];
        afr[rtg] = Qg[(u64)qi * 4 + quad];
    }
    bf16x8 bfr[8];
#pragma unroll
    for (int ct = 0; ct < 8; ct++) {
        int ki = kidx[ct * 16 + n16];
        bfr[ct] = Kg[(u64)ki * 4 + quad];
    }
    // stage V transposed: one thread per row, 3 vector loads (64 B-aligned rows)
    if (t < 128) {
        int ki = kidx[t];
        const bf16x8* vr = (const bf16x8*)(varrB + ((u64)h * NPT + ki) * 32);
        bf16x8 v0 = vr[0], v1 = vr[1], v2 = vr[2];
#pragma unroll
        for (int e = 0; e < 8; e++) {
            sVt[e * VT_STRIDE + t]        = v0[e];
            sVt[(8 + e) * VT_STRIDE + t]  = v1[e];
            sVt[(16 + e) * VT_STRIDE + t] = v2[e];
        }
    }
    __syncthreads();

    floatx4 acc[2][8];
#pragma unroll
    for (int rtg = 0; rtg < 2; rtg++)
#pragma unroll
        for (int ct = 0; ct < 8; ct++)
            acc[rtg][ct] = (floatx4){0.f, 0.f, 0.f, 0.f};
#pragma unroll
    for (int ct = 0; ct < 8; ct++) {
#pragma unroll
        for (int rtg = 0; rtg < 2; rtg++)
            acc[rtg][ct] = __builtin_amdgcn_mfma_f32_16x16x32_bf16(afr[rtg], bfr[ct], acc[rtg][ct], 0, 0, 0);
    }

    float mrow[2][4], srow[2][4];
#pragma unroll
    for (int rtg = 0; rtg < 2; rtg++) {
#pragma unroll
        for (int rg = 0; rg < 4; rg++) {
            float m = -1e30f;
#pragma unroll
            for (int ct = 0; ct < 8; ct++) m = fmaxf(m, acc[rtg][ct][rg]);
            m = fmaxf(m, __shfl_xor(m, 1));
            m = fmaxf(m, __shfl_xor(m, 2));
            m = fmaxf(m, __shfl_xor(m, 4));
            m = fmaxf(m, __shfl_xor(m, 8));
            mrow[rtg][rg] = m;
            float s = 0.0f;
            int row = wave * 32 + rtg * 16 + quad * 4 + rg;
#pragma unroll
            for (int ct = 0; ct < 8; ct++) {
                float p = __expf(acc[rtg][ct][rg] - m);
                s += p;
                if (ct < 4) sP[row * P_STRIDE + ct * 16 + n16] = (short)f2bf(p);
            }
            s += __shfl_xor(s, 1);
            s += __shfl_xor(s, 2);
            s += __shfl_xor(s, 4);
            s += __shfl_xor(s, 8);
            srow[rtg][rg] = s;
        }
    }

    floatx4 occ[2][2];
#pragma unroll
    for (int rtg = 0; rtg < 2; rtg++)
#pragma unroll
        for (int ct2 = 0; ct2 < 2; ct2++)
            occ[rtg][ct2] = (floatx4){0.f, 0.f, 0.f, 0.f};
#pragma unroll
    for (int ks = 0; ks < 2; ks++) {
        bf16x8 bv[2], av[2];
#pragma unroll
        for (int ct2 = 0; ct2 < 2; ct2++)
            bv[ct2] = *(const bf16x8*)(sVt + (ct2 * 16 + n16) * VT_STRIDE + ks * 32 + quad * 8);
#pragma unroll
        for (int rtg = 0; rtg < 2; rtg++)
            av[rtg] = *(const bf16x8*)(sP + (wave * 32 + rtg * 16 + n16) * P_STRIDE + ks * 32 + quad * 8);
#pragma unroll
        for (int rtg = 0; rtg < 2; rtg++)
#pragma unroll
            for (int ct2 = 0; ct2 < 2; ct2++)
                occ[rtg][ct2] = __builtin_amdgcn_mfma_f32_16x16x32_bf16(av[rtg], bv[ct2], occ[rtg][ct2], 0, 0, 0);
    }
#pragma unroll
    for (int rtg = 0; rtg < 2; rtg++) {
#pragma unroll
        for (int rg = 0; rg < 4; rg++) {
            int row = wave * 32 + rtg * 16 + quad * 4 + rg;
#pragma unroll
            for (int ct = 4; ct < 8; ct++) {
                float p = __expf(acc[rtg][ct][rg] - mrow[rtg][rg]);
                sP[row * P_STRIDE + (ct - 4) * 16 + n16] = (short)f2bf(p);
            }
        }
    }
#pragma unroll
    for (int ks = 2; ks < 4; ks++) {
        bf16x8 bv[2], av[2];
#pragma unroll
        for (int ct2 = 0; ct2 < 2; ct2++)
            bv[ct2] = *(const bf16x8*)(sVt + (ct2 * 16 + n16) * VT_STRIDE + ks * 32 + quad * 8);
#pragma unroll
        for (int rtg = 0; rtg < 2; rtg++)
            av[rtg] = *(const bf16x8*)(sP + (wave * 32 + rtg * 16 + n16) * P_STRIDE + (ks - 2) * 32 + quad * 8);
#pragma unroll
        for (int rtg = 0; rtg < 2; rtg++)
#pragma unroll
            for (int ct2 = 0; ct2 < 2; ct2++)
                occ[rtg][ct2] = __builtin_amdgcn_mfma_f32_16x16x32_bf16(av[rtg], bv[ct2], occ[rtg][ct2], 0, 0, 0);
    }

#pragma unroll
    for (int rtg = 0; rtg < 2; rtg++) {
#pragma unroll
        for (int rg = 0; rg < 4; rg++) {
            int row = wave * 32 + rtg * 16 + quad * 4 + rg;
            int oi = qidx[row];
            float inv = 1.0f / srow[rtg][rg];
            ushort* orow = ozB + ((u64)segQ * NPT + oi) * 32;
#pragma unroll
            for (int ct2 = 0; ct2 < 2; ct2++) {
                int col = ct2 * 16 + n16;
                if (col < 24) orow[col] = f2bf(occ[rtg][ct2][rg] * inv);
            }
            if (n16 == 0)
                *(float*)(orow + 24) = mrow[rtg][rg] + __logf(srow[rtg][rg]);
        }
    }
}

// ---------------- K4: hash combine + Wo + residual + LN2 + FFN (fp32, 32 pts/block) ----------------
#define K4PTS 32
#define AT_STR 196   // floats; 16B-aligned rows, 4-bank row offset
__global__ __launch_bounds__(256) void k4_final(
    const ushort* __restrict__ ozB,
    const float* __restrict__ x,
    const float* __restrict__ Wo, const float* __restrict__ bo,
    const float* __restrict__ g2, const float* __restrict__ b2,
    const float* __restrict__ W1, const float* __restrict__ b1f,
    const float* __restrict__ W2, const float* __restrict__ b2f,
    float* __restrict__ out) {
    __shared__ __align__(16) float sWoT[24][AT_STR];
    __shared__ float sW1[24 * 24], sW2[24 * 24];
    __shared__ float sB[5 * 24];
    __shared__ __align__(16) float attn[K4PTS][AT_STR];
    __shared__ float xrow[K4PTS][25];
    __shared__ float h2row[K4PTS][25];
    __shared__ float ffrow[K4PTS][25];
    int t = threadIdx.x;
    int base = blockIdx.x * K4PTS;
    for (int i = t; i < 4608; i += 256) sWoT[i % 24][i / 24] = Wo[i];
    for (int i = t; i < 576; i += 256) { sW1[i] = W1[i]; sW2[i] = W2[i]; }
    if (t < 24) {
        sB[t] = bo[t]; sB[24 + t] = g2[t]; sB[48 + t] = b2[t];
        sB[72 + t] = b1f[t]; sB[96 + t] = b2f[t];
    }
    {
        int p = t >> 3, h = t & 7;
        int n = base + p;
        const ushort* r0 = ozB + ((u64)(0 * 8 + h) * NPT + n) * 32;
        const ushort* r1 = ozB + ((u64)(1 * 8 + h) * NPT + n) * 32;
        const ushort* r2 = ozB + ((u64)(2 * 8 + h) * NPT + n) * 32;
        float z0 = *(const float*)(r0 + 24);
        float z1 = *(const float*)(r1 + 24);
        float z2 = *(const float*)(r2 + 24);
        float zm = fmaxf(z0, fmaxf(z1, z2));
        float e0 = __expf(z0 - zm), e1 = __expf(z1 - zm), e2 = __expf(z2 - zm);
        float inv = 1.0f / (e0 + e1 + e2);
        float w0 = e0 * inv, w1 = e1 * inv, w2 = e2 * inv;
#pragma unroll
        for (int e = 0; e < 24; e++)
            attn[p][h * 24 + e] = w0 * us2f(r0[e]) + w1 * us2f(r1[e]) + w2 * us2f(r2[e]);
    }
    __syncthreads();
    int p = t >> 3, oe = t & 7;
    int n = base + p;
    {
        const floatx4* ap = (const floatx4*)&attn[p][0];
        const floatx4* w0p = (const floatx4*)&sWoT[oe][0];
        const floatx4* w1p = (const floatx4*)&sWoT[oe + 8][0];
        const floatx4* w2p = (const floatx4*)&sWoT[oe + 16][0];
        floatx4 A0 = {0.f, 0.f, 0.f, 0.f}, A1 = A0, A2 = A0;
        for (int ii = 0; ii < 48; ii++) {
            floatx4 av = ap[ii];
            A0 += av * w0p[ii];
            A1 += av * w1p[ii];
            A2 += av * w2p[ii];
        }
        float a0 = A0[0] + A0[1] + A0[2] + A0[3];
        float a1 = A1[0] + A1[1] + A1[2] + A1[3];
        float a2 = A2[0] + A2[1] + A2[2] + A2[3];
        xrow[p][oe]      = x[n * 24 + oe]      + a0 + sB[oe];
        xrow[p][oe + 8]  = x[n * 24 + oe + 8]  + a1 + sB[oe + 8];
        xrow[p][oe + 16] = x[n * 24 + oe + 16] + a2 + sB[oe + 16];
    }
    float mu, rstd;
    {
        float s = xrow[p][oe] + xrow[p][oe + 8] + xrow[p][oe + 16];
        s += __shfl_xor(s, 1); s += __shfl_xor(s, 2); s += __shfl_xor(s, 4);
        mu = s / 24.0f;
        float v0 = xrow[p][oe] - mu, v1 = xrow[p][oe + 8] - mu, v2 = xrow[p][oe + 16] - mu;
        float v = v0 * v0 + v1 * v1 + v2 * v2;
        v += __shfl_xor(v, 1); v += __shfl_xor(v, 2); v += __shfl_xor(v, 4);
        rstd = 1.0f / sqrtf(v / 24.0f + 1e-5f);
    }
    h2row[p][oe]      = (xrow[p][oe] - mu)      * rstd * sB[24 + oe]      + sB[48 + oe];
    h2row[p][oe + 8]  = (xrow[p][oe + 8] - mu)  * rstd * sB[24 + oe + 8]  + sB[48 + oe + 8];
    h2row[p][oe + 16] = (xrow[p][oe + 16] - mu) * rstd * sB[24 + oe + 16] + sB[48 + oe + 16];
    {
        float a0 = sB[72 + oe], a1 = sB[72 + oe + 8], a2 = sB[72 + oe + 16];
        for (int i = 0; i < 24; i++) {
            float hi = h2row[p][i];
            a0 += hi * sW1[i * 24 + oe];
            a1 += hi * sW1[i * 24 + oe + 8];
            a2 += hi * sW1[i * 24 + oe + 16];
        }
        ffrow[p][oe]      = fmaxf(a0, 0.f);
        ffrow[p][oe + 8]  = fmaxf(a1, 0.f);
        ffrow[p][oe + 16] = fmaxf(a2, 0.f);
    }
    {
        float a0 = sB[96 + oe], a1 = sB[96 + oe + 8], a2 = sB[96 + oe + 16];
        for (int i = 0; i < 24; i++) {
            float fi = ffrow[p][i];
            a0 += fi * sW2[i * 24 + oe];
            a1 += fi * sW2[i * 24 + oe + 8];
            a2 += fi * sW2[i * 24 + oe + 16];
        }
        out[n * 24 + oe]      = xrow[p][oe]      + a0;
        out[n * 24 + oe + 8]  = xrow[p][oe + 8]  + a1;
        out[n * 24 + oe + 16] = xrow[p][oe + 16] + a2;
    }
}

extern "C" void kernel_launch(void* const* d_in, const int* in_sizes, int n_in,
                              void* d_out, int out_size, void* d_ws, size_t ws_size,
                              hipStream_t stream) {
    const float* x      = (const float*)d_in[0];
    const float* coords = (const float*)d_in[1];
    const float* n1g    = (const float*)d_in[2];
    const float* n1b    = (const float*)d_in[3];
    const float* Wq     = (const float*)d_in[4];
    const float* Wk     = (const float*)d_in[5];
    const float* Wv     = (const float*)d_in[6];
    const float* wrpe   = (const float*)d_in[7];
    const float* Wo     = (const float*)d_in[8];
    const float* bo     = (const float*)d_in[9];
    const float* n2g    = (const float*)d_in[10];
    const float* n2b    = (const float*)d_in[11];
    const float* W1     = (const float*)d_in[12];
    const float* b1     = (const float*)d_in[13];
    const float* W2     = (const float*)d_in[14];
    const float* b2     = (const float*)d_in[15];
    const float* alphas = (const float*)d_in[16];

    char* ws = (char*)d_ws;
    size_t off = 0;
    auto alloc = [&](size_t bytes) -> void* {
        void* p = ws + off;
        off = (off + bytes + 255) & ~(size_t)255;
        return p;
    };
    double* w64   = (double*)alloc(256);
    double* cqp   = (double*)alloc(256);
    double* Aq    = (double*)alloc(24 * NRH * 8);
    double* Ak    = (double*)alloc(24 * NRH * 8);
    double* ct    = (double*)alloc(NRH * 4 * 8);
    float*  xnf   = (float*)alloc((size_t)NPT * 24 * 4);
    ushort* qhatB = (ushort*)alloc((size_t)NH * NPT * 32 * 2);
    ushort* khatB = (ushort*)alloc((size_t)NH * NPT * 32 * 2);
    ushort* varrB = (ushort*)alloc((size_t)NH * NPT * 32 * 2);
    u64*    keys  = (u64*)alloc((size_t)NSEG * NPT * 8);
    ushort* ozB   = (ushort*)alloc((size_t)NHASH * NH * NPT * 32 * 2);
    if (off > ws_size) return;

    k0b<<<1, 256, 0, stream>>>(wrpe, Wq, Wk, alphas, w64, cqp, Aq, Ak, ct);
    k1b<<<NPT / 64, 256, 0, stream>>>(x, n1g, n1b, xnf);
    k2s<<<NPT / 64, 512, 0, stream>>>(x, n1g, n1b, coords, Aq, Ak, ct, w64, keys);
    k2p<<<NPT / K2P_PTS, 640, 0, stream>>>(xnf, Wq, Wk, Wv, coords, w64, cqp,
                                           qhatB, khatB, varrB);
    sort_local_full<<<192, 1024, 0, stream>>>(keys);
    sort_global_pass<<<3072, 256, 0, stream>>>(keys, 16384, 8192);
    sort_local_tail<<<192, 1024, 0, stream>>>(keys, 16384, 1);
    sort_global2<<<NSEG * 8192 / 256, 256, 0, stream>>>(keys);
    sort_local_tail<<<192, 1024, 0, stream>>>(keys, 32768, 128);
    k3_attn<<<256 * 8 * 3, 256, 0, stream>>>(keys, qhatB, khatB, varrB, ozB);
    k4_final<<<NPT / K4PTS, 256, 0, stream>>>(ozB, x, Wo, bo, n2g, n2b,
                                              W1, b1, W2, b2, (float*)d_out);
}

// Round 16
// 307.631 us; speedup vs baseline: 1.1632x; 1.0438x over previous
//
#include <hip/hip_runtime.h>
#include <math.h>

#define NPT 32768
#define NH 8
#define HD 24
#define EDIM 28
#define NHASH 3
#define NSEG 48
#define NRH 24   // N_HASHES * NUM_HEADS = 24 alpha rows

typedef unsigned long long u64;
typedef unsigned short ushort;
typedef __attribute__((__vector_size__(8 * sizeof(short)))) short bf16x8;
typedef __attribute__((__vector_size__(4 * sizeof(float)))) float floatx4;

__device__ __forceinline__ ushort f2bf(float f) {
    unsigned u = __float_as_uint(f);
    unsigned r = u + 0x7FFF + ((u >> 16) & 1);
    return (ushort)(r >> 16);
}
__device__ __forceinline__ float us2f(ushort u) {
    return __uint_as_float(((unsigned)u) << 16);
}

// ---------------- K0b: RPE weights + folded score matrices (fp64) ----------------
__global__ __launch_bounds__(256) void k0b(
    const float* __restrict__ wrpe, const float* __restrict__ Wq,
    const float* __restrict__ Wk, const float* __restrict__ alphas,
    double* __restrict__ w64, double* __restrict__ cqp64,
    double* __restrict__ Aq, double* __restrict__ Ak, double* __restrict__ ct) {
    __shared__ double sw[16], sc[16];
    int t = threadIdx.x;
    if (t < 16) {
        int h = t >> 1, c = t & 1;
        double s = 0.0;
        for (int i = 0; i < 24; i++)
            for (int j = 0; j < 8; j++)
                s += (double)wrpe[(h * 24 + i) * 16 + c * 8 + j];
        double m = s / 192.0;
        sw[t] = m * m;
        sc[t] = sqrt(2.0) * fabs(m);
        w64[t] = sw[t];
        cqp64[t] = sc[t];
    }
    __syncthreads();
    const double QSCALE = 1.0 / sqrt(24.0);
    for (int idx = t; idx < 24 * NRH; idx += 256) {
        int i = idx / NRH, rh = idx % NRH;
        int h = rh & 7;
        double aq = 0.0, ak = 0.0;
        for (int e = 0; e < 24; e++) {
            double al = (double)alphas[rh * 28 + e];
            aq += (double)Wq[i * 192 + h * 24 + e] * al;
            ak += (double)Wk[i * 192 + h * 24 + e] * al;
        }
        Aq[idx] = aq * QSCALE;
        Ak[idx] = ak;
    }
    if (t < NRH) {
        int h = t & 7;
        ct[t * 4 + 0] = (double)alphas[t * 28 + 24] * sc[h * 2 + 0];
        ct[t * 4 + 1] = (double)alphas[t * 28 + 25] * sc[h * 2 + 1];
        ct[t * 4 + 2] = (double)alphas[t * 28 + 26];
        ct[t * 4 + 3] = (double)alphas[t * 28 + 27];
    }
}

// ---------------- K2s: fused fp64 LN + hash scores + xnf emit ----------------
__global__ __launch_bounds__(512) void k2s(
    const float* __restrict__ x, const float* __restrict__ n1g,
    const float* __restrict__ n1b, const float* __restrict__ coords,
    const double* __restrict__ Aq, const double* __restrict__ Ak,
    const double* __restrict__ ct, const double* __restrict__ w64,
    u64* __restrict__ keys, float* __restrict__ xnf) {
    __shared__ double sA[2][24][NRH];
    __shared__ double sCt[NRH][4];
    __shared__ double sW64[16];
    __shared__ double sGB[48];
    __shared__ double sXn[8][24];
    int t = threadIdx.x;
    for (int i = t; i < 24 * NRH; i += 512) sA[0][i / NRH][i % NRH] = Aq[i];
    for (int i = t; i < 24 * NRH; i += 512) sA[1][i / NRH][i % NRH] = Ak[i];
    for (int i = t; i < NRH * 4; i += 512) sCt[i / 4][i % 4] = ct[i];
    if (t < 16) sW64[t] = w64[t];
    if (t < 24) { sGB[t] = (double)n1g[t]; sGB[24 + t] = (double)n1b[t]; }
    __syncthreads();
    int wv = t >> 6, l = t & 63;
    for (int g = 0; g < 8; g++) {
        int n = blockIdx.x * 64 + g * 8 + wv;
        double xv = (l < 24) ? (double)x[(u64)n * 24 + l] : 0.0;
        double s = xv;
        s += __shfl_xor(s, 1); s += __shfl_xor(s, 2); s += __shfl_xor(s, 4);
        s += __shfl_xor(s, 8); s += __shfl_xor(s, 16);
        double mu = s / 24.0;
        double d = (l < 24) ? (xv - mu) : 0.0;
        double v2 = d * d;
        v2 += __shfl_xor(v2, 1); v2 += __shfl_xor(v2, 2); v2 += __shfl_xor(v2, 4);
        v2 += __shfl_xor(v2, 8); v2 += __shfl_xor(v2, 16);
        double rstd = 1.0 / sqrt(v2 / 24.0 + 1e-5);
        if (l < 24) {
            double xn = d * rstd * sGB[l] + sGB[24 + l];
            sXn[wv][l] = xn;
            xnf[(u64)n * 24 + l] = (float)xn;
        }
        // no barrier: sXn[wv] written and read by the same wave only
        double p0 = (double)coords[(u64)n * 3 + 1];
        double p1 = (double)coords[(u64)n * 3 + 2];
        if (l < 2 * NRH) {
            int qk = l / NRH, rh = l % NRH;
            int h = rh & 7;
            double sqn = sW64[2 * h] * p0 * p0 + sW64[2 * h + 1] * p1 * p1;
            double acc = sCt[rh][0] * p0 + sCt[rh][1] * p1;
            acc += qk ? (sCt[rh][2] - sqn * sCt[rh][3]) : (sCt[rh][3] - sqn * sCt[rh][2]);
            for (int i = 0; i < 24; i++) acc += sXn[wv][i] * sA[qk][i][rh];
            u64 u = (u64)__double_as_longlong(acc);
            if (u >> 63) u = ~u; else u |= 0x8000000000000000ULL;
            u64 key = (u & ~(u64)32767) | (u64)n;
            keys[(u64)l * NPT + n] = key;  // segment = qk*24 + rh = l
        }
    }
}

// ---------------- K2p: column-in-VGPR projections, zero LDS ----------------
#define K2P_PTS 64
__global__ __launch_bounds__(640) void k2p(
    const float* __restrict__ xnf,
    const float* __restrict__ Wq, const float* __restrict__ Wk,
    const float* __restrict__ Wv, const float* __restrict__ coords,
    const double* __restrict__ w64, const double* __restrict__ cqp64,
    ushort* __restrict__ qhatB, ushort* __restrict__ khatB, ushort* __restrict__ varrB) {
    int t = threadIdx.x;
    int n0 = blockIdx.x * K2P_PTS;
    if (t < 576) {
        int m = t / 192, jj = t % 192;
        const float* W = (m == 0) ? Wq : ((m == 1) ? Wk : Wv);
        float wc[24];
#pragma unroll
        for (int i = 0; i < 24; i++) wc[i] = W[i * 192 + jj];
        const float scale = (m == 0) ? (float)(1.0 / sqrt(24.0)) : 1.0f;
        int h = jj / 24, e = jj % 24;
        ushort* outp = (m == 0) ? qhatB : ((m == 1) ? khatB : varrB);
        ushort* obase = outp + (u64)h * NPT * 32 + e;
        for (int p = 0; p < K2P_PTS; p++) {
            int n = n0 + p;
            const float* xr = xnf + (u64)n * 24;   // wave-uniform -> s_load
            float acc = 0.f;
#pragma unroll
            for (int i = 0; i < 24; i++) acc += xr[i] * wc[i];
            obase[(u64)n * 32] = f2bf(acc * scale);
        }
    } else {
        int l = t - 576;
        int h2 = l >> 3, e2 = 24 + (l & 7);
        double c0 = cqp64[h2 * 2], c1 = cqp64[h2 * 2 + 1];
        double wa = w64[h2 * 2], wb = w64[h2 * 2 + 1];
        ushort* qb = qhatB + (u64)h2 * NPT * 32 + e2;
        ushort* kb = khatB + (u64)h2 * NPT * 32 + e2;
        for (int p = 0; p < K2P_PTS; p++) {
            int n = n0 + p;
            double p0 = (double)coords[(u64)n * 3 + 1];
            double p1 = (double)coords[(u64)n * 3 + 2];
            float qv, kv;
            if (e2 < 26) {
                int c = e2 - 24;
                float qp = (float)((c ? c1 : c0) * (c ? p1 : p0));
                qv = qp; kv = qp;
            } else if (e2 < 28) {
                double sqn = wa * p0 * p0 + wb * p1 * p1;
                if (e2 == 26) { qv = (float)(-sqn); kv = 1.0f; }
                else          { qv = 1.0f; kv = (float)(-sqn); }
            } else {
                qv = 0.0f; kv = 0.0f;
            }
            qb[(u64)n * 32] = f2bf(qv);
            kb[(u64)n * 32] = f2bf(kv);
        }
    }
}

// ---------------- Bitonic sort v2: register/shfl network, LDS only for j>=512 ----------------
__device__ __forceinline__ u64 shflx64(u64 v, int d) {
    int lo = __shfl_xor((int)(unsigned)v, d);
    int hi = __shfl_xor((int)(unsigned)(v >> 32), d);
    return ((u64)(unsigned)hi << 32) | (unsigned)lo;
}
__device__ __forceinline__ void cswap(u64& a, u64& b, bool up) {
    if ((a > b) == up) { u64 tmp = a; a = b; b = tmp; }
}
__device__ __forceinline__ u64* sslot(u64* s, int i) {
    int a = i << 3;
    a ^= ((a >> 9) & 7) << 4;
    return (u64*)((char*)s + a);
}
__device__ __forceinline__ void reg_passes(u64 e[8], int ib, int K, int jmax) {
    for (int j = jmax; j >= 1; j >>= 1) {
#pragma unroll
        for (int k = 0; k < 8; k++)
            if ((k & j) == 0) cswap(e[k], e[k | j], ((ib + k) & K) == 0);
    }
}
__device__ __forceinline__ void shfl_passes(u64 e[8], int t, int segoff, int K, int jhi, int jlo) {
    for (int j = jhi; j >= jlo; j >>= 1) {
        int d = j >> 3;
        bool lower = (t & d) == 0;
        bool up = ((segoff + ((t & ~d) << 3)) & K) == 0;
        bool keepmin = (lower == up);
#pragma unroll
        for (int k = 0; k < 8; k++) {
            u64 o = shflx64(e[k], d);
            bool ownsm = e[k] < o;
            e[k] = (ownsm == keepmin) ? e[k] : o;
        }
    }
}

__global__ __launch_bounds__(1024) void sort_local_full(u64* keys) {
    __shared__ u64 s[8192];
    int t = threadIdx.x;
    u64 gbase = (u64)blockIdx.x * 8192;
    int segoff = (int)(gbase & 32767);
    int ib = segoff + t * 8;
    u64 e[8];
#pragma unroll
    for (int k = 0; k < 8; k++) e[k] = keys[gbase + t * 8 + k];
    reg_passes(e, ib, 2, 1);
    reg_passes(e, ib, 4, 2);
    reg_passes(e, ib, 8, 4);
    for (int K = 16; K <= 512; K <<= 1) {
        shfl_passes(e, t, segoff, K, K >> 1, 8);
        reg_passes(e, ib, K, 4);
    }
#pragma unroll
    for (int k = 0; k < 8; k++) *sslot(s, t * 8 + k) = e[k];
    __syncthreads();
    for (int K = 1024; K <= 8192; K <<= 1) {
        for (int j = K >> 1; j >= 512; j >>= 1) {
            for (int p = t; p < 4096; p += 1024) {
                int i = ((p & ~(j - 1)) << 1) | (p & (j - 1));
                int i2 = i | j;
                bool up = (((segoff + i) & K) == 0);
                u64 a = *sslot(s, i), b = *sslot(s, i2);
                if ((a > b) == up) { *sslot(s, i) = b; *sslot(s, i2) = a; }
            }
            __syncthreads();
        }
#pragma unroll
        for (int k = 0; k < 8; k++) e[k] = *sslot(s, t * 8 + k);
        shfl_passes(e, t, segoff, K, 256, 8);
        reg_passes(e, ib, K, 4);
        if (K < 8192) {
#pragma unroll
            for (int k = 0; k < 8; k++) *sslot(s, t * 8 + k) = e[k];
            __syncthreads();
        } else {
#pragma unroll
            for (int k = 0; k < 8; k++) keys[gbase + t * 8 + k] = e[k];
        }
    }
}

// tail1 fused with the K=16384 j=8192 global pass: load own chunk + partner,
// keep min/max per element (keepmin for chunk-in-segment 0,3; max for 1,2),
// then run the K=16384 merge j=4096..1 (full sort of the 8192-chunk's role).
__global__ __launch_bounds__(1024) void sort_tail1_fused(u64* keys) {
    __shared__ u64 s[8192];
    int t = threadIdx.x;
    u64 gbase = (u64)blockIdx.x * 8192;
    u64 pbase = gbase ^ 8192ULL;          // partner chunk at distance j=8192
    int ci = (int)((gbase >> 13) & 3);    // chunk index within 32768-segment
    bool keepmin = (ci == 0) || (ci == 3);
    int segoff = (int)(gbase & 32767);
    int ib = segoff + t * 8;
    for (int i = t; i < 8192; i += 1024) {
        u64 a = keys[gbase + i];
        u64 b = keys[pbase + i];
        u64 mn = a < b ? a : b;
        u64 mx = a < b ? b : a;
        *sslot(s, i) = keepmin ? mn : mx;
    }
    __syncthreads();
    const int K = 16384;
    for (int j = 4096; j >= 512; j >>= 1) {
        for (int p = t; p < 4096; p += 1024) {
            int i = ((p & ~(j - 1)) << 1) | (p & (j - 1));
            int i2 = i | j;
            bool up = (((segoff + i) & K) == 0);
            u64 a = *sslot(s, i), b = *sslot(s, i2);
            if ((a > b) == up) { *sslot(s, i) = b; *sslot(s, i2) = a; }
        }
        __syncthreads();
    }
    u64 e[8];
#pragma unroll
    for (int k = 0; k < 8; k++) e[k] = *sslot(s, t * 8 + k);
    shfl_passes(e, t, segoff, K, 256, 8);
    reg_passes(e, ib, K, 4);
#pragma unroll
    for (int k = 0; k < 8; k++) keys[gbase + t * 8 + k] = e[k];
}

// minj: stop once minj-blocks are rank-correct sets (bitonic-merge property)
__global__ __launch_bounds__(1024) void sort_local_tail(u64* keys, int K, int minj) {
    __shared__ u64 s[8192];
    int t = threadIdx.x;
    u64 gbase = (u64)blockIdx.x * 8192;
    int segoff = (int)(gbase & 32767);
    int ib = segoff + t * 8;
    for (int i = t; i < 8192; i += 1024) *sslot(s, i) = keys[gbase + i];
    __syncthreads();
    for (int j = 4096; j >= 512; j >>= 1) {
        for (int p = t; p < 4096; p += 1024) {
            int i = ((p & ~(j - 1)) << 1) | (p & (j - 1));
            int i2 = i | j;
            bool up = (((segoff + i) & K) == 0);
            u64 a = *sslot(s, i), b = *sslot(s, i2);
            if ((a > b) == up) { *sslot(s, i) = b; *sslot(s, i2) = a; }
        }
        __syncthreads();
    }
    u64 e[8];
#pragma unroll
    for (int k = 0; k < 8; k++) e[k] = *sslot(s, t * 8 + k);
    shfl_passes(e, t, segoff, K, 256, minj >= 8 ? minj : 8);
    if (minj < 8) reg_passes(e, ib, K, 4);
#pragma unroll
    for (int k = 0; k < 8; k++) keys[gbase + t * 8 + k] = e[k];
}

// fused K=32768 passes j=16384 + j=8192
__global__ void sort_global2(u64* keys) {
    int p = blockIdx.x * blockDim.x + threadIdx.x;
    if (p >= NSEG * 8192) return;
    int seg = p >> 13, c = p & 8191;
    u64 base = (u64)seg * 32768 + c;
    u64 e0 = keys[base];
    u64 e1 = keys[base + 8192];
    u64 e2 = keys[base + 16384];
    u64 e3 = keys[base + 24576];
    u64 tmp;
    if (e0 > e2) { tmp = e0; e0 = e2; e2 = tmp; }
    if (e1 > e3) { tmp = e1; e1 = e3; e3 = tmp; }
    if (e0 > e1) { tmp = e0; e0 = e1; e1 = tmp; }
    if (e2 > e3) { tmp = e2; e2 = e3; e3 = tmp; }
    keys[base] = e0;
    keys[base + 8192] = e1;
    keys[base + 16384] = e2;
    keys[base + 24576] = e3;
}

// ---------------- K3: block attention via bf16 MFMA ----------------
#define VT_STRIDE 136
#define P_STRIDE 72
__global__ __launch_bounds__(256, 4) void k3_attn(
    const u64* __restrict__ keys, const ushort* __restrict__ qhatB,
    const ushort* __restrict__ khatB, const ushort* __restrict__ varrB,
    ushort* __restrict__ ozB) {
    int rh3 = blockIdx.x % 24;
    int b = blockIdx.x / 24;
    int h = rh3 & 7, r = rh3 >> 3;
    __shared__ __align__(16) char smem[6528 + 18432 + 1024];
    short* sVt = (short*)smem;
    short* sP  = (short*)(smem + 6528);
    int* qidx  = (int*)(smem + 6528 + 18432);
    int* kidx  = qidx + 128;
    int t = threadIdx.x;
    int segQ = r * 8 + h, segK = 24 + r * 8 + h;
    if (t < 128) {
        qidx[t] = (int)(keys[(u64)segQ * NPT + b * 128 + t] & 32767ULL);
    } else {
        int i = t - 128;
        kidx[i] = (int)(keys[(u64)segK * NPT + b * 128 + i] & 32767ULL);
    }
    __syncthreads();

    int wave = t >> 6, L = t & 63;
    int quad = L >> 4, n16 = L & 15;

    const bf16x8* Qg = (const bf16x8*)(qhatB + (u64)h * NPT * 32);
    const bf16x8* Kg = (const bf16x8*)(khatB + (u64)h * NPT * 32);
    bf16x8 afr[2];
#pragma unroll
    for (int rtg = 0; rtg < 2; rtg++) {
        int qi = qidx[wave * 32 + rtg * 16 + n16];
        afr[rtg] = Qg[(u64)qi * 4 + quad];
    }
    bf16x8 bfr[8];
#pragma unroll
    for (int ct = 0; ct < 8; ct++) {
        int ki = kidx[ct * 16 + n16];
        bfr[ct] = Kg[(u64)ki * 4 + quad];
    }
    // stage V transposed: one thread per row, 3 vector loads (64 B-aligned rows)
    if (t < 128) {
        int ki = kidx[t];
        const bf16x8* vr = (const bf16x8*)(varrB + ((u64)h * NPT + ki) * 32);
        bf16x8 v0 = vr[0], v1 = vr[1], v2 = vr[2];
#pragma unroll
        for (int e = 0; e < 8; e++) {
            sVt[e * VT_STRIDE + t]        = v0[e];
            sVt[(8 + e) * VT_STRIDE + t]  = v1[e];
            sVt[(16 + e) * VT_STRIDE + t] = v2[e];
        }
    }
    __syncthreads();

    floatx4 acc[2][8];
#pragma unroll
    for (int rtg = 0; rtg < 2; rtg++)
#pragma unroll
        for (int ct = 0; ct < 8; ct++)
            acc[rtg][ct] = (floatx4){0.f, 0.f, 0.f, 0.f};
#pragma unroll
    for (int ct = 0; ct < 8; ct++) {
#pragma unroll
        for (int rtg = 0; rtg < 2; rtg++)
            acc[rtg][ct] = __builtin_amdgcn_mfma_f32_16x16x32_bf16(afr[rtg], bfr[ct], acc[rtg][ct], 0, 0, 0);
    }

    float mrow[2][4], srow[2][4];
#pragma unroll
    for (int rtg = 0; rtg < 2; rtg++) {
#pragma unroll
        for (int rg = 0; rg < 4; rg++) {
            float m = -1e30f;
#pragma unroll
            for (int ct = 0; ct < 8; ct++) m = fmaxf(m, acc[rtg][ct][rg]);
            m = fmaxf(m, __shfl_xor(m, 1));
            m = fmaxf(m, __shfl_xor(m, 2));
            m = fmaxf(m, __shfl_xor(m, 4));
            m = fmaxf(m, __shfl_xor(m, 8));
            mrow[rtg][rg] = m;
            float s = 0.0f;
            int row = wave * 32 + rtg * 16 + quad * 4 + rg;
#pragma unroll
            for (int ct = 0; ct < 8; ct++) {
                float p = __expf(acc[rtg][ct][rg] - m);
                s += p;
                if (ct < 4) sP[row * P_STRIDE + ct * 16 + n16] = (short)f2bf(p);
            }
            s += __shfl_xor(s, 1);
            s += __shfl_xor(s, 2);
            s += __shfl_xor(s, 4);
            s += __shfl_xor(s, 8);
            srow[rtg][rg] = s;
        }
    }

    floatx4 occ[2][2];
#pragma unroll
    for (int rtg = 0; rtg < 2; rtg++)
#pragma unroll
        for (int ct2 = 0; ct2 < 2; ct2++)
            occ[rtg][ct2] = (floatx4){0.f, 0.f, 0.f, 0.f};
#pragma unroll
    for (int ks = 0; ks < 2; ks++) {
        bf16x8 bv[2], av[2];
#pragma unroll
        for (int ct2 = 0; ct2 < 2; ct2++)
            bv[ct2] = *(const bf16x8*)(sVt + (ct2 * 16 + n16) * VT_STRIDE + ks * 32 + quad * 8);
#pragma unroll
        for (int rtg = 0; rtg < 2; rtg++)
            av[rtg] = *(const bf16x8*)(sP + (wave * 32 + rtg * 16 + n16) * P_STRIDE + ks * 32 + quad * 8);
#pragma unroll
        for (int rtg = 0; rtg < 2; rtg++)
#pragma unroll
            for (int ct2 = 0; ct2 < 2; ct2++)
                occ[rtg][ct2] = __builtin_amdgcn_mfma_f32_16x16x32_bf16(av[rtg], bv[ct2], occ[rtg][ct2], 0, 0, 0);
    }
#pragma unroll
    for (int rtg = 0; rtg < 2; rtg++) {
#pragma unroll
        for (int rg = 0; rg < 4; rg++) {
            int row = wave * 32 + rtg * 16 + quad * 4 + rg;
#pragma unroll
            for (int ct = 4; ct < 8; ct++) {
                float p = __expf(acc[rtg][ct][rg] - mrow[rtg][rg]);
                sP[row * P_STRIDE + (ct - 4) * 16 + n16] = (short)f2bf(p);
            }
        }
    }
#pragma unroll
    for (int ks = 2; ks < 4; ks++) {
        bf16x8 bv[2], av[2];
#pragma unroll
        for (int ct2 = 0; ct2 < 2; ct2++)
            bv[ct2] = *(const bf16x8*)(sVt + (ct2 * 16 + n16) * VT_STRIDE + ks * 32 + quad * 8);
#pragma unroll
        for (int rtg = 0; rtg < 2; rtg++)
            av[rtg] = *(const bf16x8*)(sP + (wave * 32 + rtg * 16 + n16) * P_STRIDE + (ks - 2) * 32 + quad * 8);
#pragma unroll
        for (int rtg = 0; rtg < 2; rtg++)
#pragma unroll
            for (int ct2 = 0; ct2 < 2; ct2++)
                occ[rtg][ct2] = __builtin_amdgcn_mfma_f32_16x16x32_bf16(av[rtg], bv[ct2], occ[rtg][ct2], 0, 0, 0);
    }

#pragma unroll
    for (int rtg = 0; rtg < 2; rtg++) {
#pragma unroll
        for (int rg = 0; rg < 4; rg++) {
            int row = wave * 32 + rtg * 16 + quad * 4 + rg;
            int oi = qidx[row];
            float inv = 1.0f / srow[rtg][rg];
            ushort* orow = ozB + ((u64)segQ * NPT + oi) * 32;
#pragma unroll
            for (int ct2 = 0; ct2 < 2; ct2++) {
                int col = ct2 * 16 + n16;
                if (col < 24) orow[col] = f2bf(occ[rtg][ct2][rg] * inv);
            }
            if (n16 == 0)
                *(float*)(orow + 24) = mrow[rtg][rg] + __logf(srow[rtg][rg]);
        }
    }
}

// ---------------- K4: hash combine + Wo + residual + LN2 + FFN (fp32, 32 pts/block) ----------------
#define K4PTS 32
#define AT_STR 196   // floats; 16B-aligned rows
#define W_STR 28     // transposed small-matrix row stride (16B-aligned)
__global__ __launch_bounds__(256) void k4_final(
    const ushort* __restrict__ ozB,
    const float* __restrict__ x,
    const float* __restrict__ Wo, const float* __restrict__ bo,
    const float* __restrict__ g2, const float* __restrict__ b2,
    const float* __restrict__ W1, const float* __restrict__ b1f,
    const float* __restrict__ W2, const float* __restrict__ b2f,
    float* __restrict__ out) {
    __shared__ __align__(16) float sWoT[24][AT_STR];
    __shared__ __align__(16) float sW1T[24][W_STR], sW2T[24][W_STR];
    __shared__ float sB[5 * 24];
    __shared__ __align__(16) float attn[K4PTS][AT_STR];
    __shared__ float xrow[K4PTS][25];
    __shared__ __align__(16) float h2row[K4PTS][W_STR];
    __shared__ __align__(16) float ffrow[K4PTS][W_STR];
    int t = threadIdx.x;
    int base = blockIdx.x * K4PTS;
    for (int i = t; i < 4608; i += 256) sWoT[i % 24][i / 24] = Wo[i];
    for (int i = t; i < 576; i += 256) {
        sW1T[i % 24][i / 24] = W1[i];   // sW1T[out][in]
        sW2T[i % 24][i / 24] = W2[i];
    }
    if (t < 24) {
        sB[t] = bo[t]; sB[24 + t] = g2[t]; sB[48 + t] = b2[t];
        sB[72 + t] = b1f[t]; sB[96 + t] = b2f[t];
    }
    // zero the pad columns so float4 reads over 24..27 are benign
    if (t < K4PTS * 4) {
        int p = t >> 2, c = 24 + (t & 3);
        h2row[p][c] = 0.f; ffrow[p][c] = 0.f;
    }
    if (t < 24 * 4) {
        int rr = t >> 2, c = 24 + (t & 3);
        sW1T[rr][c] = 0.f; sW2T[rr][c] = 0.f;
    }
    {
        int p = t >> 3, h = t & 7;
        int n = base + p;
        const ushort* r0 = ozB + ((u64)(0 * 8 + h) * NPT + n) * 32;
        const ushort* r1 = ozB + ((u64)(1 * 8 + h) * NPT + n) * 32;
        const ushort* r2 = ozB + ((u64)(2 * 8 + h) * NPT + n) * 32;
        float z0 = *(const float*)(r0 + 24);
        float z1 = *(const float*)(r1 + 24);
        float z2 = *(const float*)(r2 + 24);
        float zm = fmaxf(z0, fmaxf(z1, z2));
        float e0 = __expf(z0 - zm), e1 = __expf(z1 - zm), e2 = __expf(z2 - zm);
        float inv = 1.0f / (e0 + e1 + e2);
        float w0 = e0 * inv, w1 = e1 * inv, w2 = e2 * inv;
#pragma unroll
        for (int e = 0; e < 24; e++)
            attn[p][h * 24 + e] = w0 * us2f(r0[e]) + w1 * us2f(r1[e]) + w2 * us2f(r2[e]);
    }
    __syncthreads();
    int p = t >> 3, oe = t & 7;
    int n = base + p;
    {
        const floatx4* ap = (const floatx4*)&attn[p][0];
        const floatx4* w0p = (const floatx4*)&sWoT[oe][0];
        const floatx4* w1p = (const floatx4*)&sWoT[oe + 8][0];
        const floatx4* w2p = (const floatx4*)&sWoT[oe + 16][0];
        floatx4 A0 = {0.f, 0.f, 0.f, 0.f}, A1 = A0, A2 = A0;
        for (int ii = 0; ii < 48; ii++) {
            floatx4 av = ap[ii];
            A0 += av * w0p[ii];
            A1 += av * w1p[ii];
            A2 += av * w2p[ii];
        }
        float a0 = A0[0] + A0[1] + A0[2] + A0[3];
        float a1 = A1[0] + A1[1] + A1[2] + A1[3];
        float a2 = A2[0] + A2[1] + A2[2] + A2[3];
        xrow[p][oe]      = x[n * 24 + oe]      + a0 + sB[oe];
        xrow[p][oe + 8]  = x[n * 24 + oe + 8]  + a1 + sB[oe + 8];
        xrow[p][oe + 16] = x[n * 24 + oe + 16] + a2 + sB[oe + 16];
    }
    float mu, rstd;
    {
        float s = xrow[p][oe] + xrow[p][oe + 8] + xrow[p][oe + 16];
        s += __shfl_xor(s, 1); s += __shfl_xor(s, 2); s += __shfl_xor(s, 4);
        mu = s / 24.0f;
        float v0 = xrow[p][oe] - mu, v1 = xrow[p][oe + 8] - mu, v2 = xrow[p][oe + 16] - mu;
        float v = v0 * v0 + v1 * v1 + v2 * v2;
        v += __shfl_xor(v, 1); v += __shfl_xor(v, 2); v += __shfl_xor(v, 4);
        rstd = 1.0f / sqrtf(v / 24.0f + 1e-5f);
    }
    h2row[p][oe]      = (xrow[p][oe] - mu)      * rstd * sB[24 + oe]      + sB[48 + oe];
    h2row[p][oe + 8]  = (xrow[p][oe + 8] - mu)  * rstd * sB[24 + oe + 8]  + sB[48 + oe + 8];
    h2row[p][oe + 16] = (xrow[p][oe + 16] - mu) * rstd * sB[24 + oe + 16] + sB[48 + oe + 16];
    {
        const floatx4* hp = (const floatx4*)&h2row[p][0];
        const floatx4* w0p = (const floatx4*)&sW1T[oe][0];
        const floatx4* w1p = (const floatx4*)&sW1T[oe + 8][0];
        const floatx4* w2p = (const floatx4*)&sW1T[oe + 16][0];
        floatx4 A0 = {0.f, 0.f, 0.f, 0.f}, A1 = A0, A2 = A0;
#pragma unroll
        for (int ii = 0; ii < 6; ii++) {
            floatx4 hv = hp[ii];
            A0 += hv * w0p[ii];
            A1 += hv * w1p[ii];
            A2 += hv * w2p[ii];
        }
        ffrow[p][oe]      = fmaxf(A0[0]+A0[1]+A0[2]+A0[3] + sB[72 + oe], 0.f);
        ffrow[p][oe + 8]  = fmaxf(A1[0]+A1[1]+A1[2]+A1[3] + sB[72 + oe + 8], 0.f);
        ffrow[p][oe + 16] = fmaxf(A2[0]+A2[1]+A2[2]+A2[3] + sB[72 + oe + 16], 0.f);
    }
    {
        const floatx4* fp = (const floatx4*)&ffrow[p][0];
        const floatx4* w0p = (const floatx4*)&sW2T[oe][0];
        const floatx4* w1p = (const floatx4*)&sW2T[oe + 8][0];
        const floatx4* w2p = (const floatx4*)&sW2T[oe + 16][0];
        floatx4 A0 = {0.f, 0.f, 0.f, 0.f}, A1 = A0, A2 = A0;
#pragma unroll
        for (int ii = 0; ii < 6; ii++) {
            floatx4 fv = fp[ii];
            A0 += fv * w0p[ii];
            A1 += fv * w1p[ii];
            A2 += fv * w2p[ii];
        }
        out[n * 24 + oe]      = xrow[p][oe]      + A0[0]+A0[1]+A0[2]+A0[3] + sB[96 + oe];
        out[n * 24 + oe + 8]  = xrow[p][oe + 8]  + A1[0]+A1[1]+A1[2]+A1[3] + sB[96 + oe + 8];
        out[n * 24 + oe + 16] = xrow[p][oe + 16] + A2[0]+A2[1]+A2[2]+A2[3] + sB[96 + oe + 16];
    }
}

extern "C" void kernel_launch(void* const* d_in, const int* in_sizes, int n_in,
                              void* d_out, int out_size, void* d_ws, size_t ws_size,
                              hipStream_t stream) {
    const float* x      = (const float*)d_in[0];
    const float* coords = (const float*)d_in[1];
    const float* n1g    = (const float*)d_in[2];
    const float* n1b    = (const float*)d_in[3];
    const float* Wq     = (const float*)d_in[4];
    const float* Wk     = (const float*)d_in[5];
    const float* Wv     = (const float*)d_in[6];
    const float* wrpe   = (const float*)d_in[7];
    const float* Wo     = (const float*)d_in[8];
    const float* bo     = (const float*)d_in[9];
    const float* n2g    = (const float*)d_in[10];
    const float* n2b    = (const float*)d_in[11];
    const float* W1     = (const float*)d_in[12];
    const float* b1     = (const float*)d_in[13];
    const float* W2     = (const float*)d_in[14];
    const float* b2     = (const float*)d_in[15];
    const float* alphas = (const float*)d_in[16];

    char* ws = (char*)d_ws;
    size_t off = 0;
    auto alloc = [&](size_t bytes) -> void* {
        void* p = ws + off;
        off = (off + bytes + 255) & ~(size_t)255;
        return p;
    };
    double* w64   = (double*)alloc(256);
    double* cqp   = (double*)alloc(256);
    double* Aq    = (double*)alloc(24 * NRH * 8);
    double* Ak    = (double*)alloc(24 * NRH * 8);
    double* ct    = (double*)alloc(NRH * 4 * 8);
    float*  xnf   = (float*)alloc((size_t)NPT * 24 * 4);
    ushort* qhatB = (ushort*)alloc((size_t)NH * NPT * 32 * 2);
    ushort* khatB = (ushort*)alloc((size_t)NH * NPT * 32 * 2);
    ushort* varrB = (ushort*)alloc((size_t)NH * NPT * 32 * 2);
    u64*    keys  = (u64*)alloc((size_t)NSEG * NPT * 8);
    ushort* ozB   = (ushort*)alloc((size_t)NHASH * NH * NPT * 32 * 2);
    if (off > ws_size) return;

    k0b<<<1, 256, 0, stream>>>(wrpe, Wq, Wk, alphas, w64, cqp, Aq, Ak, ct);
    k2s<<<NPT / 64, 512, 0, stream>>>(x, n1g, n1b, coords, Aq, Ak, ct, w64, keys, xnf);
    k2p<<<NPT / K2P_PTS, 640, 0, stream>>>(xnf, Wq, Wk, Wv, coords, w64, cqp,
                                           qhatB, khatB, varrB);
    sort_local_full<<<192, 1024, 0, stream>>>(keys);
    sort_tail1_fused<<<192, 1024, 0, stream>>>(keys);
    sort_global2<<<NSEG * 8192 / 256, 256, 0, stream>>>(keys);
    sort_local_tail<<<192, 1024, 0, stream>>>(keys, 32768, 128);
    k3_attn<<<256 * 8 * 3, 256, 0, stream>>>(keys, qhatB, khatB, varrB, ozB);
    k4_final<<<NPT / K4PTS, 256, 0, stream>>>(ozB, x, Wo, bo, n2g, n2b,
                                              W1, b1, W2, b2, (float*)d_out);
}